// Round 7
// baseline (1707.627 us; speedup 1.0000x reference)
//
#include <hip/hip_runtime.h>

// LSPD_43404939493531: bidirectional 2-layer GRU (B=512,T=512,U=32) + BN folds + dense head.
// R12: SMT the GRU chains. R11 counters: gru1 215us, ~905 cyc/step vs ~450 cyc issue work, with
//     ONE wave per SIMD (64 single-wave blocks, waves_per_eu(1,1)) -> every DPP wait-state,
//     MFMA->VALU hazard, and trans-pipe latency is exposed. Software ILP (R10/R11 x-proj
//     pipelining) gained only 8%. Fix: co-locate 2 independent chains per SIMD so the HW
//     scheduler fills one chain's stalls with the other's issue:
//       - blocks of 512 threads (8 waves) -> one CU, 4 SIMDs, 2 waves/SIMD guaranteed;
//       - chain id = blockIdx.x*8 + waveIdx (64 chains, 8 blocks);
//       - waves_per_eu(2); VGPR 164 fits the 256/wave budget at 2 waves/EU.
//     Per-wave code is BIT-IDENTICAL to R11 (same math, same accumulation order, absmax
//     0.00390625 expected unchanged). MFMA+VALU are separate pipes (learn_hip m114: co-resident
//     waves overlap fully), so 2 chains/SIMD should cut wall time ~1.7-2x.

#define Bsz 512
#define Tsz 512

typedef unsigned uintv2 __attribute__((ext_vector_type(2)));
typedef _Float16 half8 __attribute__((ext_vector_type(8)));
typedef float f32x4 __attribute__((ext_vector_type(4)));

union H8 { unsigned u[4]; half8 h; };

__device__ __forceinline__ float sigmoid_f(float x) {
    return __builtin_amdgcn_rcpf(1.0f + __expf(-x));
}

// ---- cross-lane swaps (VALU pipe), two-result form ----
__device__ __forceinline__ uintv2 p16(unsigned a, unsigned b) {
#if __has_builtin(__builtin_amdgcn_permlane16_swap)
    return __builtin_amdgcn_permlane16_swap(a, b, false, false);
#else
    asm("v_permlane16_swap_b32 %0, %1" : "+v"(a), "+v"(b));
    uintv2 r; r.x = a; r.y = b; return r;
#endif
}
__device__ __forceinline__ uintv2 p32(unsigned a, unsigned b) {
#if __has_builtin(__builtin_amdgcn_permlane32_swap)
    return __builtin_amdgcn_permlane32_swap(a, b, false, false);
#else
    asm("v_permlane32_swap_b32 %0, %1" : "+v"(a), "+v"(b));
    uintv2 r; r.x = a; r.y = b; return r;
#endif
}

// Fixed routing network: 4 packed words (2 ch each, C-layout) -> 4 B-fragment words.
// Used identically for calibration payloads and runtime data -> semantics-agnostic.
__device__ __forceinline__ void route4(unsigned P0, unsigned P1, unsigned P2, unsigned P3,
                                       unsigned& W0, unsigned& W1, unsigned& W2, unsigned& W3)
{
    uintv2 m = p32(P0, P2);
    uintv2 a = p16(m.x, m.y);
    uintv2 n = p32(P1, P3);
    uintv2 c = p16(n.x, n.y);
    W0 = a.x; W2 = a.y; W1 = c.x; W3 = c.y;
}

__device__ __forceinline__ unsigned pk16(float a, float b) {
    auto h = __builtin_amdgcn_cvt_pkrtz(a, b);   // __fp16 ext_vector_type(2)
    return __builtin_bit_cast(unsigned, h);
}

__device__ __forceinline__ H8 make_B(float v0, float v1, float v2, float v3,
                                     float v4, float v5, float v6, float v7)
{
    unsigned P0 = pk16(v0, v1), P1 = pk16(v2, v3);
    unsigned P2 = pk16(v4, v5), P3 = pk16(v6, v7);
    H8 b;
    route4(P0, P1, P2, P3, b.u[0], b.u[1], b.u[2], b.u[3]);
    return b;
}

// calibrate: cs[e] = channel whose value lands in B-slot e (word e>>1, half e&1) for this lane
__device__ __forceinline__ void calib_slots(int lane, int cs[8]) {
    unsigned q = (unsigned)(lane >> 4) & 3u;
    unsigned c0 = 4u * q, c1 = 16u + 4u * q;
    unsigned P0 = c0 | ((c0 + 1u) << 16);
    unsigned P1 = (c0 + 2u) | ((c0 + 3u) << 16);
    unsigned P2 = c1 | ((c1 + 1u) << 16);
    unsigned P3 = (c1 + 2u) | ((c1 + 3u) << 16);
    unsigned W0, W1, W2, W3;
    route4(P0, P1, P2, P3, W0, W1, W2, W3);
    cs[0] = W0 & 0xffff; cs[1] = W0 >> 16;
    cs[2] = W1 & 0xffff; cs[3] = W1 >> 16;
    cs[4] = W2 & 0xffff; cs[5] = W2 >> 16;
    cs[6] = W3 & 0xffff; cs[7] = W3 >> 16;
}

// A-tile: row = lane&15 (gate row within tile), slot e multiplies B slot e -> load via cs[]
__device__ __forceinline__ H8 load_A(const float* __restrict__ M, const int cs[8], int gcol) {
    H8 a;
#pragma unroll
    for (int e = 0; e < 4; ++e)
        a.u[e] = pk16(M[cs[2 * e] * 96 + gcol], M[cs[2 * e + 1] * 96 + gcol]);
    return a;
}

__device__ __forceinline__ f32x4 mfma16(const H8& a, const H8& b, f32x4 c) {
    return __builtin_amdgcn_mfma_f32_16x16x32_f16(a.h, b.h, c, 0, 0, 0);
}

__device__ __forceinline__ float gate1(float az, float ar, float ah, float ai, float h) {
    float z = sigmoid_f(az);
    float r = sigmoid_f(ar);
    float hh = fmaxf(0.f, fmaf(r, ah, ai));
    return hh + z * (h - hh);
}

// ---------------- K1: argmax over D=128, one wave per (b,t), t-fastest ----------------
__global__ __launch_bounds__(256) void lspd_argmax(const float* __restrict__ x, int* __restrict__ idxT)
{
    int wv = threadIdx.x >> 6, lane = threadIdx.x & 63;
    long p = (long)blockIdx.x * 4 + wv;           // p = b*512 + t
    const float* xp = x + p * 128;
    float v0 = xp[lane];      int i0 = lane;
    float v1 = xp[64 + lane]; int i1 = 64 + lane;
    if (v1 > v0) { v0 = v1; i0 = i1; }            // ties keep lower index (first occurrence)
#pragma unroll
    for (int d = 1; d < 64; d <<= 1) {
        float ov = __shfl_xor(v0, d, 64);
        int   oi = __shfl_xor(i0, d, 64);
        if (ov > v0 || (ov == v0 && oi < i0)) { v0 = ov; i0 = oi; }
    }
    if (lane == 0) idxT[p] = i0;
}

// ---------------- K0: layer-0 input tables tab[i][g] = (emb@W0)[i][g] + b0_in[g] ----------------
__global__ __launch_bounds__(256) void lspd_tab(
    const float* __restrict__ emb, const float* __restrict__ Wl, const float* __restrict__ bl,
    const float* __restrict__ Wr, const float* __restrict__ br,
    float* __restrict__ tabL, float* __restrict__ tabR)
{
    int flat = blockIdx.x * 256 + threadIdx.x;    // 0..24575
    int dir = flat / 12288;
    int r = flat % 12288;
    int i = r / 96, g = r % 96;
    const float* W  = dir ? Wr : Wl;              // layer 0 at base
    const float* bb = dir ? br : bl;              // b[0][0] input bias at base
    float acc = bb[g];
#pragma unroll
    for (int k = 0; k < 32; ++k) acc = fmaf(emb[i * 32 + k], W[k * 96 + g], acc);
    (dir ? tabR : tabL)[r] = acc;
}

// ---------------- K2: layer-0 GRU (MFMA), 16 batch rows per wave, 8 chains per block ----------------
__global__ __launch_bounds__(512)
__attribute__((amdgpu_waves_per_eu(2)))
void lspd_gru0(
    const int* __restrict__ idxT, const float* __restrict__ tabL, const float* __restrict__ tabR,
    const float* __restrict__ Ul, const float* __restrict__ Ur,
    const float* __restrict__ bl, const float* __restrict__ br,
    float* __restrict__ Lout, float* __restrict__ Rout)
{
    int chain = blockIdx.x * 8 + (threadIdx.x >> 6);   // 0..63
    int dir = chain >> 5;
    int bg  = chain & 31;
    int lane = threadIdx.x & 63;
    int rl = lane & 15;                 // B/C col = batch; A row = gate row
    int q  = lane >> 4;
    int b  = bg * 16 + rl;
    const float* U    = dir ? Ur : Ul;
    const float* tab  = dir ? tabR : tabL;
    const float* brec = (dir ? br : bl) + 96;     // layer-0 recurrent bias
    float* out        = dir ? Rout : Lout;

    int cs[8];
    calib_slots(lane, cs);

    // recurrent A tiles (gate G in {z,r,h}, channel half hf)
    H8 AUz0 = load_A(U, cs, 0  + rl), AUz1 = load_A(U, cs, 16 + rl);
    H8 AUr0 = load_A(U, cs, 32 + rl), AUr1 = load_A(U, cs, 48 + rl);
    H8 AUh0 = load_A(U, cs, 64 + rl), AUh1 = load_A(U, cs, 80 + rl);
    // recurrent-bias C fragments: value = brec[gate_off + hf*16 + 4q + reg]
    f32x4 BZ0 = *(const f32x4*)(brec + 0  + 4 * q);
    f32x4 BZ1 = *(const f32x4*)(brec + 16 + 4 * q);
    f32x4 BR0 = *(const f32x4*)(brec + 32 + 4 * q);
    f32x4 BR1 = *(const f32x4*)(brec + 48 + 4 * q);
    f32x4 BH0 = *(const f32x4*)(brec + 64 + 4 * q);
    f32x4 BH1 = *(const f32x4*)(brec + 80 + 4 * q);

    const int* idxrow = idxT + (long)b * Tsz;

#define TT0(s) (dir ? (Tsz - 2 - (s)) : (1 + (s)))
    // boundary zero row
    {
        long zb = ((long)(dir ? Tsz - 1 : 0) * Bsz + b) * 32;
        float4 z4 = make_float4(0.f, 0.f, 0.f, 0.f);
        *(float4*)(out + zb + 4 * q) = z4;
        *(float4*)(out + zb + 16 + 4 * q) = z4;
    }
    long ob = ((long)TT0(0) * Bsz + b) * 32;
    long ostride = (long)(dir ? -1 : 1) * Bsz * 32;

    // 4-deep gather pipeline: slot j holds tab row for step j (mod 4); idx 8 ahead
    float4 G0z0, G0z1, G0r0, G0r1, G0h0, G0h1;
    float4 G1z0, G1z1, G1r0, G1r1, G1h0, G1h1;
    float4 G2z0, G2z1, G2r0, G2r1, G2h0, G2h1;
    float4 G3z0, G3z1, G3r0, G3r1, G3h0, G3h1;
#define GFILL(P, TA)                                                           \
    {                                                                          \
        long ta_ = (long)(TA) * 96;                                            \
        P##z0 = *(const float4*)(tab + ta_ + 0  + 4 * q);                      \
        P##z1 = *(const float4*)(tab + ta_ + 16 + 4 * q);                      \
        P##r0 = *(const float4*)(tab + ta_ + 32 + 4 * q);                      \
        P##r1 = *(const float4*)(tab + ta_ + 48 + 4 * q);                      \
        P##h0 = *(const float4*)(tab + ta_ + 64 + 4 * q);                      \
        P##h1 = *(const float4*)(tab + ta_ + 80 + 4 * q);                      \
    }
    GFILL(G0, idxrow[TT0(0)]);
    GFILL(G1, idxrow[TT0(1)]);
    GFILL(G2, idxrow[TT0(2)]);
    GFILL(G3, idxrow[TT0(3)]);
    int i0 = idxrow[TT0(4)];
    int i1 = idxrow[TT0(5)];
    int i2 = idxrow[TT0(6)];
    int i3 = idxrow[TT0(7)];

    float h0 = 0.f, h1 = 0.f, h2 = 0.f, h3 = 0.f, h4 = 0.f, h5 = 0.f, h6 = 0.f, h7 = 0.f;

    // step: MFMA(C=bias) -> gates(+G) -> store -> refill this slot (4 steps ahead) -> idx refill
#define STEP0(Gz0, Gz1, Gr0, Gr1, Gh0, Gh1, IREG, SINEXT)                      \
    {                                                                          \
        H8 Bh = make_B(h0, h1, h2, h3, h4, h5, h6, h7);                        \
        f32x4 Cz0 = mfma16(AUz0, Bh, BZ0);                                     \
        f32x4 Cz1 = mfma16(AUz1, Bh, BZ1);                                     \
        f32x4 Cr0 = mfma16(AUr0, Bh, BR0);                                     \
        f32x4 Cr1 = mfma16(AUr1, Bh, BR1);                                     \
        f32x4 Ch0 = mfma16(AUh0, Bh, BH0);                                     \
        f32x4 Ch1 = mfma16(AUh1, Bh, BH1);                                     \
        h0 = gate1(Cz0.x + Gz0.x, Cr0.x + Gr0.x, Ch0.x, Gh0.x, h0);            \
        h1 = gate1(Cz0.y + Gz0.y, Cr0.y + Gr0.y, Ch0.y, Gh0.y, h1);            \
        h2 = gate1(Cz0.z + Gz0.z, Cr0.z + Gr0.z, Ch0.z, Gh0.z, h2);            \
        h3 = gate1(Cz0.w + Gz0.w, Cr0.w + Gr0.w, Ch0.w, Gh0.w, h3);            \
        h4 = gate1(Cz1.x + Gz1.x, Cr1.x + Gr1.x, Ch1.x, Gh1.x, h4);            \
        h5 = gate1(Cz1.y + Gz1.y, Cr1.y + Gr1.y, Ch1.y, Gh1.y, h5);            \
        h6 = gate1(Cz1.z + Gz1.z, Cr1.z + Gr1.z, Ch1.z, Gh1.z, h6);            \
        h7 = gate1(Cz1.w + Gz1.w, Cr1.w + Gr1.w, Ch1.w, Gh1.w, h7);            \
        *(float4*)(out + ob + 4 * q) = make_float4(h0, h1, h2, h3);            \
        *(float4*)(out + ob + 16 + 4 * q) = make_float4(h4, h5, h6, h7);       \
        ob += ostride;                                                         \
        long tb2 = (long)IREG * 96;                                            \
        Gz0 = *(const float4*)(tab + tb2 + 0  + 4 * q);                        \
        Gz1 = *(const float4*)(tab + tb2 + 16 + 4 * q);                        \
        Gr0 = *(const float4*)(tab + tb2 + 32 + 4 * q);                        \
        Gr1 = *(const float4*)(tab + tb2 + 48 + 4 * q);                        \
        Gh0 = *(const float4*)(tab + tb2 + 64 + 4 * q);                        \
        Gh1 = *(const float4*)(tab + tb2 + 80 + 4 * q);                        \
        int sn = (SINEXT); if (sn > Tsz - 2) sn = Tsz - 2;                     \
        IREG = idxrow[TT0(sn)];                                                \
    }

    for (int sb = 0; sb < 508; sb += 4) {
        STEP0(G0z0, G0z1, G0r0, G0r1, G0h0, G0h1, i0, sb + 8);
        STEP0(G1z0, G1z1, G1r0, G1r1, G1h0, G1h1, i1, sb + 9);
        STEP0(G2z0, G2z1, G2r0, G2r1, G2h0, G2h1, i2, sb + 10);
        STEP0(G3z0, G3z1, G3r0, G3r1, G3h0, G3h1, i3, sb + 11);
    }
    // tail: steps 508, 509, 510 (refills clamped, dead)
    STEP0(G0z0, G0z1, G0r0, G0r1, G0h0, G0h1, i0, 510);
    STEP0(G1z0, G1z1, G1r0, G1r1, G1h0, G1h1, i1, 510);
    STEP0(G2z0, G2z1, G2r0, G2r1, G2h0, G2h1, i2, 510);
#undef STEP0
#undef GFILL
#undef TT0
}

// ---------------- K3/K5: per-channel sum & sumsq of (L+R) ----------------
__global__ __launch_bounds__(256) void lspd_stats(
    const float* __restrict__ A, const float* __restrict__ Bv, float* __restrict__ part)
{
    __shared__ float sS[256], sQ[256];
    int tid = threadIdx.x;
    size_t base = (size_t)blockIdx.x * 65536 + tid;
    float s = 0.f, q = 0.f;
    for (int i = 0; i < 256; ++i) {
        size_t ix = base + (size_t)i * 256;
        float v = A[ix] + Bv[ix];
        s += v; q = fmaf(v, v, q);
    }
    sS[tid] = s; sQ[tid] = q;
    __syncthreads();
    if (tid < 32) {
        float S = 0.f, Q = 0.f;
        for (int j = 0; j < 8; ++j) { S += sS[tid + 32 * j]; Q += sQ[tid + 32 * j]; }
        part[blockIdx.x * 64 + tid] = S;
        part[blockIdx.x * 64 + 32 + tid] = Q;
    }
}

// ---------------- K3b: fold layer-0 BN into layer-1 input weights ----------------
__global__ __launch_bounds__(256) void lspd_fold1(
    const float* __restrict__ part, const float* __restrict__ g0, const float* __restrict__ be0,
    const float* __restrict__ Wl, const float* __restrict__ Wr,
    const float* __restrict__ bl, const float* __restrict__ br,
    float* __restrict__ WpL, float* __restrict__ WpR,
    float* __restrict__ b4L, float* __restrict__ b4R)
{
    __shared__ float sc[32], tc[32];
    int tid = threadIdx.x;
    if (tid < 32) {
        float S = 0.f, Q = 0.f;
        for (int p = 0; p < 128; ++p) { S += part[p * 64 + tid]; Q += part[p * 64 + 32 + tid]; }
        const float invN = 1.0f / 262144.0f;
        float m = S * invN;
        float v = Q * invN - m * m;
        float s = g0[tid] * __builtin_amdgcn_rsqf(v + 1e-3f);
        sc[tid] = s; tc[tid] = be0[tid] - s * m;
    }
    __syncthreads();
    for (int idx = tid; idx < 6144; idx += 256) {
        int dir = idx / 3072, e = idx % 3072, k = e / 96, g = e % 96;
        const float* W1 = (dir ? Wr : Wl) + 3072;      // layer 1
        (dir ? WpR : WpL)[e] = sc[k] * W1[k * 96 + g];
    }
    {
        int idx = tid;                                  // 256 entries exactly
        int dir = idx >> 7, slot = idx & 127, sub = slot >> 5, cc = slot & 31;
        const float* bb = (dir ? br : bl) + 192;        // layer-1: [0..95]=input, [96..191]=recurrent
        const float* W1 = (dir ? Wr : Wl) + 3072;
        float r;
        if (sub == 2) {
            r = bb[96 + 64 + cc];                       // rh: recurrent h-bias only
        } else {
            int g = (sub == 3) ? (64 + cc) : (sub * 32 + cc);
            float acc = bb[g];                          // input bias
            for (int k = 0; k < 32; ++k) acc = fmaf(tc[k], W1[k * 96 + g], acc);
            if (sub < 2) acc += bb[96 + g];             // z,r: + recurrent bias
            r = acc;
        }
        (dir ? b4R : b4L)[slot] = r;
    }
}

// ---------------- K4: layer-1 GRU (MFMA), x-proj pipelined, 8 chains per block ----------------
__global__ __launch_bounds__(512)
__attribute__((amdgpu_waves_per_eu(2)))
void lspd_gru1(
    const float* __restrict__ L0, const float* __restrict__ R0,
    const float* __restrict__ WpL, const float* __restrict__ WpR,
    const float* __restrict__ b4L, const float* __restrict__ b4R,
    const float* __restrict__ Ul1, const float* __restrict__ Ur1,
    float* __restrict__ Lout, float* __restrict__ Rout)
{
    int chain = blockIdx.x * 8 + (threadIdx.x >> 6);   // 0..63
    int dir = chain >> 5;
    int bg  = chain & 31;
    int lane = threadIdx.x & 63;
    int rl = lane & 15;
    int q  = lane >> 4;
    int b  = bg * 16 + rl;
    const float* U  = dir ? Ur1 : Ul1;
    const float* Wp = dir ? WpR : WpL;
    const float* b4 = dir ? b4R : b4L;
    float* out      = dir ? Rout : Lout;

    int cs[8];
    calib_slots(lane, cs);

    H8 AWz0 = load_A(Wp, cs, 0  + rl), AWz1 = load_A(Wp, cs, 16 + rl);
    H8 AWr0 = load_A(Wp, cs, 32 + rl), AWr1 = load_A(Wp, cs, 48 + rl);
    H8 AWh0 = load_A(Wp, cs, 64 + rl), AWh1 = load_A(Wp, cs, 80 + rl);
    H8 AUz0 = load_A(U, cs, 0  + rl),  AUz1 = load_A(U, cs, 16 + rl);
    H8 AUr0 = load_A(U, cs, 32 + rl),  AUr1 = load_A(U, cs, 48 + rl);
    H8 AUh0 = load_A(U, cs, 64 + rl),  AUh1 = load_A(U, cs, 80 + rl);
    // bias fragments: b4 = [z total(32) | r total(32) | rh rec-bias(32) | ih folded(32)]
    f32x4 BZ0 = *(const f32x4*)(b4 + 0   + 4 * q);
    f32x4 BZ1 = *(const f32x4*)(b4 + 16  + 4 * q);
    f32x4 BR0 = *(const f32x4*)(b4 + 32  + 4 * q);
    f32x4 BR1 = *(const f32x4*)(b4 + 48  + 4 * q);
    f32x4 BH0 = *(const f32x4*)(b4 + 64  + 4 * q);
    f32x4 BH1 = *(const f32x4*)(b4 + 80  + 4 * q);
    f32x4 BI0 = *(const f32x4*)(b4 + 96  + 4 * q);
    f32x4 BI1 = *(const f32x4*)(b4 + 112 + 4 * q);

#define XBASE(s) (((long)(dir ? (Tsz - 2 - (s)) : (1 + (s))) * Bsz + b) * 32)
    {
        long zb = ((long)(dir ? Tsz - 1 : 0) * Bsz + b) * 32;
        float4 z4 = make_float4(0.f, 0.f, 0.f, 0.f);
        *(float4*)(out + zb + 4 * q) = z4;
        *(float4*)(out + zb + 16 + 4 * q) = z4;
    }
    long ob = XBASE(0);
    long ostride = (long)(dir ? -1 : 1) * Bsz * 32;

    // P double-buffer: x-projection results (z,r chained-base; i = ih incl folded bias)
    f32x4 PAz0, PAz1, PAr0, PAr1, PAi0, PAi1;
    f32x4 PBz0, PBz1, PBr0, PBr1, PBi0, PBi1;
    // prologue: P_A for step 0 from x(0)
    {
        long n0 = XBASE(0);
        float4 ta = *(const float4*)(L0 + n0 + 4 * q);
        float4 tb = *(const float4*)(L0 + n0 + 16 + 4 * q);
        float4 tc = *(const float4*)(R0 + n0 + 4 * q);
        float4 td = *(const float4*)(R0 + n0 + 16 + 4 * q);
        H8 Bx = make_B(ta.x + tc.x, ta.y + tc.y, ta.z + tc.z, ta.w + tc.w,
                       tb.x + td.x, tb.y + td.y, tb.z + td.z, tb.w + td.w);
        PAz0 = mfma16(AWz0, Bx, BZ0);
        PAz1 = mfma16(AWz1, Bx, BZ1);
        PAr0 = mfma16(AWr0, Bx, BR0);
        PAr1 = mfma16(AWr1, Bx, BR1);
        PAi0 = mfma16(AWh0, Bx, BI0);
        PAi1 = mfma16(AWh1, Bx, BI1);
    }
    // x slots j=0..3 hold x(1+j); slot used at step s (s%4==j) for Bx(s+1), refilled <- x(s+5)
    float4 la0, lb0, ra0, rb0, la1, lb1, ra1, rb1;
    float4 la2, lb2, ra2, rb2, la3, lb3, ra3, rb3;
    {
        long n1 = XBASE(1);
        la0 = *(const float4*)(L0 + n1 + 4 * q); lb0 = *(const float4*)(L0 + n1 + 16 + 4 * q);
        ra0 = *(const float4*)(R0 + n1 + 4 * q); rb0 = *(const float4*)(R0 + n1 + 16 + 4 * q);
        long n2 = XBASE(2);
        la1 = *(const float4*)(L0 + n2 + 4 * q); lb1 = *(const float4*)(L0 + n2 + 16 + 4 * q);
        ra1 = *(const float4*)(R0 + n2 + 4 * q); rb1 = *(const float4*)(R0 + n2 + 16 + 4 * q);
        long n3 = XBASE(3);
        la2 = *(const float4*)(L0 + n3 + 4 * q); lb2 = *(const float4*)(L0 + n3 + 16 + 4 * q);
        ra2 = *(const float4*)(R0 + n3 + 4 * q); rb2 = *(const float4*)(R0 + n3 + 16 + 4 * q);
        long n4 = XBASE(4);
        la3 = *(const float4*)(L0 + n4 + 4 * q); lb3 = *(const float4*)(L0 + n4 + 16 + 4 * q);
        ra3 = *(const float4*)(R0 + n4 + 4 * q); rb3 = *(const float4*)(R0 + n4 + 16 + 4 * q);
    }
    float h0 = 0.f, h1 = 0.f, h2 = 0.f, h3 = 0.f, h4 = 0.f, h5 = 0.f, h6 = 0.f, h7 = 0.f;

    // step s: consume P (made from x(s)); produce Q (for s+1) from slot = x(s+1); refill slot.
    // Critical path: make_B(h) -> 1 chained MFMA -> gates. Q-production fills hazard window.
#define STEP1(XLA, XLB, XRA, XRB, Pz0, Pz1, Pr0, Pr1, Pi0, Pi1,                \
              Qz0, Qz1, Qr0, Qr1, Qi0, Qi1, SNEXT)                             \
    {                                                                          \
        H8 Bh = make_B(h0, h1, h2, h3, h4, h5, h6, h7);                        \
        f32x4 Cz0 = mfma16(AUz0, Bh, Pz0);                                     \
        f32x4 Cz1 = mfma16(AUz1, Bh, Pz1);                                     \
        f32x4 Cr0 = mfma16(AUr0, Bh, Pr0);                                     \
        f32x4 Cr1 = mfma16(AUr1, Bh, Pr1);                                     \
        f32x4 Ch0 = mfma16(AUh0, Bh, BH0);                                     \
        f32x4 Ch1 = mfma16(AUh1, Bh, BH1);                                     \
        H8 Bx = make_B(XLA.x + XRA.x, XLA.y + XRA.y, XLA.z + XRA.z,            \
                       XLA.w + XRA.w, XLB.x + XRB.x, XLB.y + XRB.y,            \
                       XLB.z + XRB.z, XLB.w + XRB.w);                          \
        Qz0 = mfma16(AWz0, Bx, BZ0);                                           \
        Qz1 = mfma16(AWz1, Bx, BZ1);                                           \
        Qr0 = mfma16(AWr0, Bx, BR0);                                           \
        Qr1 = mfma16(AWr1, Bx, BR1);                                           \
        Qi0 = mfma16(AWh0, Bx, BI0);                                           \
        Qi1 = mfma16(AWh1, Bx, BI1);                                           \
        int sn = (SNEXT); if (sn > Tsz - 2) sn = Tsz - 2;                      \
        long nb = XBASE(sn);                                                   \
        XLA = *(const float4*)(L0 + nb + 4 * q);                               \
        XLB = *(const float4*)(L0 + nb + 16 + 4 * q);                          \
        XRA = *(const float4*)(R0 + nb + 4 * q);                               \
        XRB = *(const float4*)(R0 + nb + 16 + 4 * q);                          \
        h0 = gate1(Cz0.x, Cr0.x, Ch0.x, Pi0.x, h0);                            \
        h1 = gate1(Cz0.y, Cr0.y, Ch0.y, Pi0.y, h1);                            \
        h2 = gate1(Cz0.z, Cr0.z, Ch0.z, Pi0.z, h2);                            \
        h3 = gate1(Cz0.w, Cr0.w, Ch0.w, Pi0.w, h3);                            \
        h4 = gate1(Cz1.x, Cr1.x, Ch1.x, Pi1.x, h4);                            \
        h5 = gate1(Cz1.y, Cr1.y, Ch1.y, Pi1.y, h5);                            \
        h6 = gate1(Cz1.z, Cr1.z, Ch1.z, Pi1.z, h6);                            \
        h7 = gate1(Cz1.w, Cr1.w, Ch1.w, Pi1.w, h7);                            \
        *(float4*)(out + ob + 4 * q) = make_float4(h0, h1, h2, h3);            \
        *(float4*)(out + ob + 16 + 4 * q) = make_float4(h4, h5, h6, h7);       \
        ob += ostride;                                                         \
    }

    for (int sb = 0; sb < 508; sb += 4) {
        STEP1(la0, lb0, ra0, rb0,
              PAz0, PAz1, PAr0, PAr1, PAi0, PAi1,
              PBz0, PBz1, PBr0, PBr1, PBi0, PBi1, sb + 5);
        STEP1(la1, lb1, ra1, rb1,
              PBz0, PBz1, PBr0, PBr1, PBi0, PBi1,
              PAz0, PAz1, PAr0, PAr1, PAi0, PAi1, sb + 6);
        STEP1(la2, lb2, ra2, rb2,
              PAz0, PAz1, PAr0, PAr1, PAi0, PAi1,
              PBz0, PBz1, PBr0, PBr1, PBi0, PBi1, sb + 7);
        STEP1(la3, lb3, ra3, rb3,
              PBz0, PBz1, PBr0, PBr1, PBi0, PBi1,
              PAz0, PAz1, PAr0, PAr1, PAi0, PAi1, sb + 8);
    }
    // tail: steps 508, 509, 510 (Q production + refills are dead/clamped)
    STEP1(la0, lb0, ra0, rb0,
          PAz0, PAz1, PAr0, PAr1, PAi0, PAi1,
          PBz0, PBz1, PBr0, PBr1, PBi0, PBi1, 510);
    STEP1(la1, lb1, ra1, rb1,
          PBz0, PBz1, PBr0, PBr1, PBi0, PBi1,
          PAz0, PAz1, PAr0, PAr1, PAi0, PAi1, 510);
    STEP1(la2, lb2, ra2, rb2,
          PAz0, PAz1, PAr0, PAr1, PAi0, PAi1,
          PBz0, PBz1, PBr0, PBr1, PBi0, PBi1, 510);
#undef STEP1
#undef XBASE
}

// ---------------- K5b: fold layer-1 BN into dense-1 weights ----------------
__global__ __launch_bounds__(256) void lspd_fold2(
    const float* __restrict__ part, const float* __restrict__ g1, const float* __restrict__ be1,
    const float* __restrict__ Wd1, const float* __restrict__ bd1,
    float* __restrict__ Wdp, float* __restrict__ bdp)
{
    __shared__ float sc[32], tc[32];
    int tid = threadIdx.x;
    if (tid < 32) {
        float S = 0.f, Q = 0.f;
        for (int p = 0; p < 128; ++p) { S += part[p * 64 + tid]; Q += part[p * 64 + 32 + tid]; }
        const float invN = 1.0f / 262144.0f;
        float m = S * invN;
        float v = Q * invN - m * m;
        float s = g1[tid] * __builtin_amdgcn_rsqf(v + 1e-3f);
        sc[tid] = s; tc[tid] = be1[tid] - s * m;
    }
    __syncthreads();
    for (int idx = tid; idx < 1024; idx += 256) {
        int k = idx >> 5;
        Wdp[idx] = sc[k] * Wd1[idx];
    }
    if (tid < 32) {
        float acc = bd1[tid];
        for (int k = 0; k < 32; ++k) acc = fmaf(tc[k], Wd1[k * 32 + tid], acc);
        bdp[tid] = acc;
    }
}

// ---------------- K6: dense + per-t batch BN + classifier + softmax; one block per t ----------------
__global__ __launch_bounds__(512) void lspd_final(
    const float* __restrict__ L1a, const float* __restrict__ R1a,
    const float* __restrict__ Wdp, const float* __restrict__ bdp,
    const float* __restrict__ dg, const float* __restrict__ db,
    const float* __restrict__ Wf, const float* __restrict__ bfv,
    float* __restrict__ outp)
{
    __shared__ alignas(16) float sW[1024];
    __shared__ float sb[32], sWf[352], sbf[16], sS[32], sT[32];
    __shared__ float redS[8][32], redQ[8][32];
    int tid = threadIdx.x, t = blockIdx.x;
    for (int i = tid; i < 1024; i += 512) sW[i] = Wdp[i];
    if (tid < 32)  sb[tid] = bdp[tid];
    if (tid < 352) sWf[tid] = Wf[tid];
    if (tid < 11)  sbf[tid] = bfv[tid];
    __syncthreads();

    size_t base = ((size_t)t * Bsz + tid) * 32;
    float xv[32];
#pragma unroll
    for (int c2 = 0; c2 < 32; c2 += 4) {
        float4 a = *(const float4*)(L1a + base + c2);
        float4 b = *(const float4*)(R1a + base + c2);
        xv[c2 + 0] = a.x + b.x; xv[c2 + 1] = a.y + b.y;
        xv[c2 + 2] = a.z + b.z; xv[c2 + 3] = a.w + b.w;
    }
    float o[32];
#pragma unroll
    for (int g = 0; g < 32; ++g) o[g] = sb[g];
#pragma unroll
    for (int k = 0; k < 32; ++k) {
        float xk = xv[k];
#pragma unroll
        for (int g4 = 0; g4 < 8; ++g4) {
            float4 w = *(const float4*)(sW + k * 32 + g4 * 4);   // same-address LDS broadcast
            o[g4 * 4 + 0] = fmaf(xk, w.x, o[g4 * 4 + 0]);
            o[g4 * 4 + 1] = fmaf(xk, w.y, o[g4 * 4 + 1]);
            o[g4 * 4 + 2] = fmaf(xk, w.z, o[g4 * 4 + 2]);
            o[g4 * 4 + 3] = fmaf(xk, w.w, o[g4 * 4 + 3]);
        }
    }
#pragma unroll
    for (int g = 0; g < 32; ++g) o[g] = fmaxf(o[g], 0.f);

    // per-(t,channel) stats over batch (within block)
    int wv = tid >> 6, lane = tid & 63;
    for (int g = 0; g < 32; ++g) {
        float s = o[g], q = o[g] * o[g];
        for (int d = 1; d < 64; d <<= 1) {
            s += __shfl_xor(s, d, 64);
            q += __shfl_xor(q, d, 64);
        }
        if (lane == 0) { redS[wv][g] = s; redQ[wv][g] = q; }
    }
    __syncthreads();
    if (tid < 32) {
        float S = 0.f, Q = 0.f;
        for (int w2 = 0; w2 < 8; ++w2) { S += redS[w2][tid]; Q += redQ[w2][tid]; }
        float m = S * (1.0f / 512.0f);
        float v = Q * (1.0f / 512.0f) - m * m;
        float s = dg[tid] * __builtin_amdgcn_rsqf(v + 1e-3f);
        sS[tid] = s; sT[tid] = db[tid] - s * m;
    }
    __syncthreads();

    float lg[11];
#pragma unroll
    for (int n = 0; n < 11; ++n) lg[n] = sbf[n];
#pragma unroll
    for (int g = 0; g < 32; ++g) {
        float no = fmaf(o[g], sS[g], sT[g]);
#pragma unroll
        for (int n = 0; n < 11; ++n) lg[n] = fmaf(no, sWf[g * 11 + n], lg[n]);
    }
    float mx = lg[0];
#pragma unroll
    for (int n = 1; n < 11; ++n) mx = fmaxf(mx, lg[n]);
    float sum = 0.f;
#pragma unroll
    for (int n = 0; n < 11; ++n) { lg[n] = __expf(lg[n] - mx); sum += lg[n]; }
    float inv = __builtin_amdgcn_rcpf(sum);
    float* op = outp + ((size_t)tid * Tsz + t) * 11;
#pragma unroll
    for (int n = 0; n < 11; ++n) op[n] = lg[n] * inv;
}

extern "C" void kernel_launch(void* const* d_in, const int* in_sizes, int n_in,
                              void* d_out, int out_size, void* d_ws, size_t ws_size,
                              hipStream_t stream)
{
    (void)in_sizes; (void)n_in; (void)out_size; (void)ws_size;
    const float* x   = (const float*)d_in[0];
    const float* emb = (const float*)d_in[1];
    const float* Wl  = (const float*)d_in[2];
    const float* Ul  = (const float*)d_in[3];
    const float* bl  = (const float*)d_in[4];
    const float* Wr  = (const float*)d_in[5];
    const float* Ur  = (const float*)d_in[6];
    const float* br  = (const float*)d_in[7];
    const float* bng = (const float*)d_in[8];
    const float* bnb = (const float*)d_in[9];
    const float* Wd  = (const float*)d_in[10];
    const float* bd  = (const float*)d_in[11];
    const float* dg  = (const float*)d_in[12];
    const float* db  = (const float*)d_in[13];
    const float* Wf  = (const float*)d_in[14];
    const float* bf  = (const float*)d_in[15];
    float* out = (float*)d_out;

    float* ws = (float*)d_ws;
    float* L0 = ws;
    float* R0 = L0 + 8388608;
    float* L1 = R0 + 8388608;
    float* R1 = L1 + 8388608;
    float* rest = R1 + 8388608;
    int* idxT   = (int*)rest;            // 262144 ints
    float* tabL = rest + 262144;
    float* tabR = tabL + 12288;
    float* part1 = tabR + 12288;         // 8192
    float* part2 = part1 + 8192;         // 8192
    float* WpL = part2 + 8192;           // 3072
    float* WpR = WpL + 3072;
    float* b4L = WpR + 3072;             // 128
    float* b4R = b4L + 128;
    float* Wdp = b4R + 128;              // 1024
    float* bdp = Wdp + 1024;             // 32

    lspd_argmax<<<65536, 256, 0, stream>>>(x, idxT);
    lspd_tab<<<96, 256, 0, stream>>>(emb, Wl, bl, Wr, br, tabL, tabR);
    lspd_gru0<<<8, 512, 0, stream>>>(idxT, tabL, tabR, Ul, Ur, bl, br, L0, R0);
    lspd_stats<<<128, 256, 0, stream>>>(L0, R0, part1);
    lspd_fold1<<<1, 256, 0, stream>>>(part1, bng, bnb, Wl, Wr, bl, br, WpL, WpR, b4L, b4R);
    lspd_gru1<<<8, 512, 0, stream>>>(L0, R0, WpL, WpR, b4L, b4R, Ul + 3072, Ur + 3072, L1, R1);
    lspd_stats<<<128, 256, 0, stream>>>(L1, R1, part2);
    lspd_fold2<<<1, 256, 0, stream>>>(part2, bng + 32, bnb + 32, Wd + 1024, bd + 32, Wdp, bdp);
    lspd_final<<<512, 512, 0, stream>>>(L1, R1, Wdp, bdp, dg + 32, db + 32, Wf, bf, out);
}

// Round 8
// 673.398 us; speedup vs baseline: 2.5358x; 2.5358x over previous
//
#include <hip/hip_runtime.h>

// LSPD_43404939493531: bidirectional 2-layer GRU (B=512,T=512,U=32) + BN folds + dense head.
// R13: best-known mix after R12's co-residency failure (8 blocks x 512thr put all chains on 8 CUs;
//     gru0's per-lane scattered tab-gathers serialized on 8 CUs' TA pipes -> 834us, per-SIMD
//     VALUBusy 33%). Revert to per-kernel winners, both spread wide:
//       - gru0: R7 VALU form (1024 waves = 1 chain per (b,dir) per wave over 256 CUs; permlane
//         swap + DPP row_newbcast broadcasts; wave-uniform tab rows -> coalesced loads).
//         Measured-in-total ~140-170us.
//       - gru1: R11 MFMA form (64 waves, 16 batch/wave, mfma_f32_16x16x32_f16, x-proj pipelined
//         one step ahead via P double-buffer; waves_per_eu(1,1)). Measured 215us.
//     Everything else (argmax/tab/stats/folds/final) unchanged from the 649us R7 baseline.

#define Bsz 512
#define Tsz 512

typedef unsigned uintv2 __attribute__((ext_vector_type(2)));
typedef _Float16 half8 __attribute__((ext_vector_type(8)));
typedef float f32x4 __attribute__((ext_vector_type(4)));

union H8 { unsigned u[4]; half8 h; };

__device__ __forceinline__ float sigmoid_f(float x) {
    return __builtin_amdgcn_rcpf(1.0f + __expf(-x));
}

// ---- cross-lane swaps (VALU pipe), two-result form ----
__device__ __forceinline__ uintv2 p16(unsigned a, unsigned b) {
#if __has_builtin(__builtin_amdgcn_permlane16_swap)
    return __builtin_amdgcn_permlane16_swap(a, b, false, false);
#else
    asm("v_permlane16_swap_b32 %0, %1" : "+v"(a), "+v"(b));
    uintv2 r; r.x = a; r.y = b; return r;
#endif
}
__device__ __forceinline__ uintv2 p32(unsigned a, unsigned b) {
#if __has_builtin(__builtin_amdgcn_permlane32_swap)
    return __builtin_amdgcn_permlane32_swap(a, b, false, false);
#else
    asm("v_permlane32_swap_b32 %0, %1" : "+v"(a), "+v"(b));
    uintv2 r; r.x = a; r.y = b; return r;
#endif
}

// ---- R7 VALU-GRU primitives (gru0) ----
__device__ __forceinline__ void plswap16_f(float& a, float& b) {
    uintv2 r = p16(__float_as_uint(a), __float_as_uint(b));
    a = __uint_as_float(r.x);
    b = __uint_as_float(r.y);
}
__device__ __forceinline__ void plswap16_i(int& a, int& b) {
    uintv2 r = p16((unsigned)a, (unsigned)b);
    a = (int)r.x;
    b = (int)r.y;
}
__device__ __forceinline__ float xhalfsum(float a) {   // a[lane] + a[lane^32]
    uintv2 r = p32(__float_as_uint(a), __float_as_uint(a));
    return __uint_as_float(r.x) + __uint_as_float(r.y);
}

// DPP row_newbcast:n (ctrl 0x150+n): broadcast in-row lane n to the whole 16-lane row
#define NB_F(d, s, n) d = __int_as_float(__builtin_amdgcn_update_dpp(0, __float_as_int(s), 0x150 + n, 0xF, 0xF, true))
#define NB_I(d, s, n) d = __builtin_amdgcn_update_dpp(0, (s), 0x150 + n, 0xF, 0xF, true)
#define BCAST16F(A, S)                                                         \
    NB_F(A[0], S, 0);  NB_F(A[1], S, 1);  NB_F(A[2], S, 2);  NB_F(A[3], S, 3); \
    NB_F(A[4], S, 4);  NB_F(A[5], S, 5);  NB_F(A[6], S, 6);  NB_F(A[7], S, 7); \
    NB_F(A[8], S, 8);  NB_F(A[9], S, 9);  NB_F(A[10], S, 10); NB_F(A[11], S, 11); \
    NB_F(A[12], S, 12); NB_F(A[13], S, 13); NB_F(A[14], S, 14); NB_F(A[15], S, 15)
#define BCAST16I(A, S)                                                         \
    NB_I(A[0], S, 0);  NB_I(A[1], S, 1);  NB_I(A[2], S, 2);  NB_I(A[3], S, 3); \
    NB_I(A[4], S, 4);  NB_I(A[5], S, 5);  NB_I(A[6], S, 6);  NB_I(A[7], S, 7); \
    NB_I(A[8], S, 8);  NB_I(A[9], S, 9);  NB_I(A[10], S, 10); NB_I(A[11], S, 11); \
    NB_I(A[12], S, 12); NB_I(A[13], S, 13); NB_I(A[14], S, 14); NB_I(A[15], S, 15)

// ---- R11 MFMA-GRU primitives (gru1) ----
// Fixed routing network: 4 packed words (2 ch each, C-layout) -> 4 B-fragment words.
__device__ __forceinline__ void route4(unsigned P0, unsigned P1, unsigned P2, unsigned P3,
                                       unsigned& W0, unsigned& W1, unsigned& W2, unsigned& W3)
{
    uintv2 m = p32(P0, P2);
    uintv2 a = p16(m.x, m.y);
    uintv2 n = p32(P1, P3);
    uintv2 c = p16(n.x, n.y);
    W0 = a.x; W2 = a.y; W1 = c.x; W3 = c.y;
}

__device__ __forceinline__ unsigned pk16(float a, float b) {
    auto h = __builtin_amdgcn_cvt_pkrtz(a, b);   // __fp16 ext_vector_type(2)
    return __builtin_bit_cast(unsigned, h);
}

__device__ __forceinline__ H8 make_B(float v0, float v1, float v2, float v3,
                                     float v4, float v5, float v6, float v7)
{
    unsigned P0 = pk16(v0, v1), P1 = pk16(v2, v3);
    unsigned P2 = pk16(v4, v5), P3 = pk16(v6, v7);
    H8 b;
    route4(P0, P1, P2, P3, b.u[0], b.u[1], b.u[2], b.u[3]);
    return b;
}

// calibrate: cs[e] = channel whose value lands in B-slot e for this lane
__device__ __forceinline__ void calib_slots(int lane, int cs[8]) {
    unsigned q = (unsigned)(lane >> 4) & 3u;
    unsigned c0 = 4u * q, c1 = 16u + 4u * q;
    unsigned P0 = c0 | ((c0 + 1u) << 16);
    unsigned P1 = (c0 + 2u) | ((c0 + 3u) << 16);
    unsigned P2 = c1 | ((c1 + 1u) << 16);
    unsigned P3 = (c1 + 2u) | ((c1 + 3u) << 16);
    unsigned W0, W1, W2, W3;
    route4(P0, P1, P2, P3, W0, W1, W2, W3);
    cs[0] = W0 & 0xffff; cs[1] = W0 >> 16;
    cs[2] = W1 & 0xffff; cs[3] = W1 >> 16;
    cs[4] = W2 & 0xffff; cs[5] = W2 >> 16;
    cs[6] = W3 & 0xffff; cs[7] = W3 >> 16;
}

// A-tile: row = lane&15 (gate row within tile), slot e multiplies B slot e -> load via cs[]
__device__ __forceinline__ H8 load_A(const float* __restrict__ M, const int cs[8], int gcol) {
    H8 a;
#pragma unroll
    for (int e = 0; e < 4; ++e)
        a.u[e] = pk16(M[cs[2 * e] * 96 + gcol], M[cs[2 * e + 1] * 96 + gcol]);
    return a;
}

__device__ __forceinline__ f32x4 mfma16(const H8& a, const H8& b, f32x4 c) {
    return __builtin_amdgcn_mfma_f32_16x16x32_f16(a.h, b.h, c, 0, 0, 0);
}

__device__ __forceinline__ float gate1(float az, float ar, float ah, float ai, float h) {
    float z = sigmoid_f(az);
    float r = sigmoid_f(ar);
    float hh = fmaxf(0.f, fmaf(r, ah, ai));
    return hh + z * (h - hh);
}

// ---------------- K1: argmax over D=128, one wave per (b,t), t-fastest ----------------
__global__ __launch_bounds__(256) void lspd_argmax(const float* __restrict__ x, int* __restrict__ idxT)
{
    int wv = threadIdx.x >> 6, lane = threadIdx.x & 63;
    long p = (long)blockIdx.x * 4 + wv;           // p = b*512 + t
    const float* xp = x + p * 128;
    float v0 = xp[lane];      int i0 = lane;
    float v1 = xp[64 + lane]; int i1 = 64 + lane;
    if (v1 > v0) { v0 = v1; i0 = i1; }            // ties keep lower index (first occurrence)
#pragma unroll
    for (int d = 1; d < 64; d <<= 1) {
        float ov = __shfl_xor(v0, d, 64);
        int   oi = __shfl_xor(i0, d, 64);
        if (ov > v0 || (ov == v0 && oi < i0)) { v0 = ov; i0 = oi; }
    }
    if (lane == 0) idxT[p] = i0;
}

// ---------------- K0: layer-0 input tables tab[i][g] = (emb@W0)[i][g] + b0_in[g] ----------------
__global__ __launch_bounds__(256) void lspd_tab(
    const float* __restrict__ emb, const float* __restrict__ Wl, const float* __restrict__ bl,
    const float* __restrict__ Wr, const float* __restrict__ br,
    float* __restrict__ tabL, float* __restrict__ tabR)
{
    int flat = blockIdx.x * 256 + threadIdx.x;    // 0..24575
    int dir = flat / 12288;
    int r = flat % 12288;
    int i = r / 96, g = r % 96;
    const float* W  = dir ? Wr : Wl;              // layer 0 at base
    const float* bb = dir ? br : bl;              // b[0][0] input bias at base
    float acc = bb[g];
#pragma unroll
    for (int k = 0; k < 32; ++k) acc = fmaf(emb[i * 32 + k], W[k * 96 + g], acc);
    (dir ? tabR : tabL)[r] = acc;
}

// ---------------- K2: layer-0 GRU (R7 VALU form), 1 chain per wave, 1024 waves ----------------
__global__ __launch_bounds__(64)
__attribute__((amdgpu_waves_per_eu(1, 1)))
void lspd_gru0(
    const int* __restrict__ idxT, const float* __restrict__ tabL, const float* __restrict__ tabR,
    const float* __restrict__ Ul, const float* __restrict__ Ur,
    const float* __restrict__ bl, const float* __restrict__ br,
    float* __restrict__ Lout, float* __restrict__ Rout)
{
    int wid = blockIdx.x;
    int dir = wid >> 9;
    int b = wid & 511;
    int lane = threadIdx.x;
    int half = lane >> 5, c = lane & 31;
    const float* U    = dir ? Ur : Ul;
    const float* tab  = dir ? tabR : tabL;
    const float* brec = (dir ? br : bl) + 96;     // layer-0 recurrent bias b[0][1]
    float* out        = dir ? Rout : Lout;

    // ---- permutation self-calibration: kk[j] = channel whose h lands in hk[j] ----
    int ksA = c, ksB = c;
    plswap16_i(ksA, ksB);
    bool selA = ((ksA >> 4) == half);
    int ksel = selA ? ksA : ksB;
    int kk[16];
    BCAST16I(kk, ksel);

    float u0[16], u1[16], u2[16];
#pragma unroll
    for (int j = 0; j < 16; ++j) {
        u0[j] = U[kk[j] * 96 + c];
        u1[j] = U[kk[j] * 96 + 32 + c];
        u2[j] = U[kk[j] * 96 + 64 + c];
    }
    float bZ = half ? 0.f : brec[c];
    float bR = half ? 0.f : brec[32 + c];
    float bH = half ? 0.f : brec[64 + c];
#pragma unroll
    for (int j = 0; j < 16; ++j) {
        asm volatile("" : "+v"(u0[j]), "+v"(u1[j]), "+v"(u2[j]));
    }
    asm volatile("" : "+v"(bZ), "+v"(bR), "+v"(bH));

    const int* idxrow = idxT + (long)b * Tsz;
    if (lane < 32) out[(((long)(dir ? Tsz - 1 : 0)) * Bsz + b) * 32 + c] = 0.f;  // boundary zero

#define TT0(s) (dir ? (Tsz - 2 - (s)) : (1 + (s)))
    long ob = ((long)TT0(0) * Bsz + b) * 32 + c;
    long ostride = (long)(dir ? -1 : 1) * Bsz * 32;

    // 4-slot gi pipeline (gather 4 steps ahead), idx 8 ahead
    float g0z, g0r, g0h, g1z, g1r, g1h, g2z, g2r, g2h, g3z, g3r, g3h;
    { int i = idxrow[TT0(0)]; g0z = tab[i * 96 + c]; g0r = tab[i * 96 + 32 + c]; g0h = tab[i * 96 + 64 + c]; }
    { int i = idxrow[TT0(1)]; g1z = tab[i * 96 + c]; g1r = tab[i * 96 + 32 + c]; g1h = tab[i * 96 + 64 + c]; }
    { int i = idxrow[TT0(2)]; g2z = tab[i * 96 + c]; g2r = tab[i * 96 + 32 + c]; g2h = tab[i * 96 + 64 + c]; }
    { int i = idxrow[TT0(3)]; g3z = tab[i * 96 + c]; g3r = tab[i * 96 + 32 + c]; g3h = tab[i * 96 + 64 + c]; }
    int i0 = idxrow[TT0(4)];
    int i1 = idxrow[TT0(5)];
    int i2 = idxrow[TT0(6)];
    int i3 = idxrow[TT0(7)];
    float h = 0.f;

#define GSTEP(GZ, GR, GH, IREG, SNEXT)                                         \
    {                                                                          \
        float ha = h, hb = h;                                                  \
        plswap16_f(ha, hb);                                                    \
        float hs = selA ? ha : hb;                                             \
        float hk[16];                                                          \
        BCAST16F(hk, hs);                                                      \
        float az = bZ, ar = bR, ah = bH;                                       \
        _Pragma("unroll")                                                      \
        for (int n = 0; n < 16; ++n) {                                         \
            az = fmaf(hk[n], u0[n], az);                                       \
            ar = fmaf(hk[n], u1[n], ar);                                       \
            ah = fmaf(hk[n], u2[n], ah);                                       \
        }                                                                      \
        az = xhalfsum(az); ar = xhalfsum(ar); ah = xhalfsum(ah);               \
        float z = sigmoid_f(az + GZ);                                          \
        float r = sigmoid_f(ar + GR);                                          \
        float hh = fmaxf(0.f, fmaf(r, ah, GH));                                \
        h = hh + z * (h - hh);                                                 \
        if (lane < 32) out[ob] = h;                                            \
        ob += ostride;                                                         \
        GZ = tab[IREG * 96 + c];                                               \
        GR = tab[IREG * 96 + 32 + c];                                          \
        GH = tab[IREG * 96 + 64 + c];                                          \
        int sn = (SNEXT); if (sn > Tsz - 2) sn = Tsz - 2;                      \
        IREG = idxrow[TT0(sn)];                                                \
    }

    for (int sb = 0; sb < 508; sb += 4) {
        GSTEP(g0z, g0r, g0h, i0, sb + 8);
        GSTEP(g1z, g1r, g1h, i1, sb + 9);
        GSTEP(g2z, g2r, g2h, i2, sb + 10);
        GSTEP(g3z, g3r, g3h, i3, sb + 11);
    }
    // tail: steps 508, 509, 510 (refills are clamped duplicates, dead)
    GSTEP(g0z, g0r, g0h, i0, 510);
    GSTEP(g1z, g1r, g1h, i1, 510);
    GSTEP(g2z, g2r, g2h, i2, 510);
#undef GSTEP
#undef TT0
}

// ---------------- K3/K5: per-channel sum & sumsq of (L+R) ----------------
__global__ __launch_bounds__(256) void lspd_stats(
    const float* __restrict__ A, const float* __restrict__ Bv, float* __restrict__ part)
{
    __shared__ float sS[256], sQ[256];
    int tid = threadIdx.x;
    size_t base = (size_t)blockIdx.x * 65536 + tid;
    float s = 0.f, q = 0.f;
    for (int i = 0; i < 256; ++i) {
        size_t ix = base + (size_t)i * 256;
        float v = A[ix] + Bv[ix];
        s += v; q = fmaf(v, v, q);
    }
    sS[tid] = s; sQ[tid] = q;
    __syncthreads();
    if (tid < 32) {
        float S = 0.f, Q = 0.f;
        for (int j = 0; j < 8; ++j) { S += sS[tid + 32 * j]; Q += sQ[tid + 32 * j]; }
        part[blockIdx.x * 64 + tid] = S;
        part[blockIdx.x * 64 + 32 + tid] = Q;
    }
}

// ---------------- K3b: fold layer-0 BN into layer-1 input weights ----------------
__global__ __launch_bounds__(256) void lspd_fold1(
    const float* __restrict__ part, const float* __restrict__ g0, const float* __restrict__ be0,
    const float* __restrict__ Wl, const float* __restrict__ Wr,
    const float* __restrict__ bl, const float* __restrict__ br,
    float* __restrict__ WpL, float* __restrict__ WpR,
    float* __restrict__ b4L, float* __restrict__ b4R)
{
    __shared__ float sc[32], tc[32];
    int tid = threadIdx.x;
    if (tid < 32) {
        float S = 0.f, Q = 0.f;
        for (int p = 0; p < 128; ++p) { S += part[p * 64 + tid]; Q += part[p * 64 + 32 + tid]; }
        const float invN = 1.0f / 262144.0f;
        float m = S * invN;
        float v = Q * invN - m * m;
        float s = g0[tid] * __builtin_amdgcn_rsqf(v + 1e-3f);
        sc[tid] = s; tc[tid] = be0[tid] - s * m;
    }
    __syncthreads();
    for (int idx = tid; idx < 6144; idx += 256) {
        int dir = idx / 3072, e = idx % 3072, k = e / 96, g = e % 96;
        const float* W1 = (dir ? Wr : Wl) + 3072;      // layer 1
        (dir ? WpR : WpL)[e] = sc[k] * W1[k * 96 + g];
    }
    {
        int idx = tid;                                  // 256 entries exactly
        int dir = idx >> 7, slot = idx & 127, sub = slot >> 5, cc = slot & 31;
        const float* bb = (dir ? br : bl) + 192;        // layer-1: [0..95]=input, [96..191]=recurrent
        const float* W1 = (dir ? Wr : Wl) + 3072;
        float r;
        if (sub == 2) {
            r = bb[96 + 64 + cc];                       // rh: recurrent h-bias only
        } else {
            int g = (sub == 3) ? (64 + cc) : (sub * 32 + cc);
            float acc = bb[g];                          // input bias
            for (int k = 0; k < 32; ++k) acc = fmaf(tc[k], W1[k * 96 + g], acc);
            if (sub < 2) acc += bb[96 + g];             // z,r: + recurrent bias
            r = acc;
        }
        (dir ? b4R : b4L)[slot] = r;
    }
}

// ---------------- K4: layer-1 GRU (R11 MFMA form), 16 batch rows per wave, 64 waves ----------------
__global__ __launch_bounds__(64)
__attribute__((amdgpu_waves_per_eu(1, 1)))
void lspd_gru1(
    const float* __restrict__ L0, const float* __restrict__ R0,
    const float* __restrict__ WpL, const float* __restrict__ WpR,
    const float* __restrict__ b4L, const float* __restrict__ b4R,
    const float* __restrict__ Ul1, const float* __restrict__ Ur1,
    float* __restrict__ Lout, float* __restrict__ Rout)
{
    int bid = blockIdx.x;
    int dir = bid >> 5;
    int bg  = bid & 31;
    int lane = threadIdx.x;
    int rl = lane & 15;
    int q  = lane >> 4;
    int b  = bg * 16 + rl;
    const float* U  = dir ? Ur1 : Ul1;
    const float* Wp = dir ? WpR : WpL;
    const float* b4 = dir ? b4R : b4L;
    float* out      = dir ? Rout : Lout;

    int cs[8];
    calib_slots(lane, cs);

    H8 AWz0 = load_A(Wp, cs, 0  + rl), AWz1 = load_A(Wp, cs, 16 + rl);
    H8 AWr0 = load_A(Wp, cs, 32 + rl), AWr1 = load_A(Wp, cs, 48 + rl);
    H8 AWh0 = load_A(Wp, cs, 64 + rl), AWh1 = load_A(Wp, cs, 80 + rl);
    H8 AUz0 = load_A(U, cs, 0  + rl),  AUz1 = load_A(U, cs, 16 + rl);
    H8 AUr0 = load_A(U, cs, 32 + rl),  AUr1 = load_A(U, cs, 48 + rl);
    H8 AUh0 = load_A(U, cs, 64 + rl),  AUh1 = load_A(U, cs, 80 + rl);
    // bias fragments: b4 = [z total(32) | r total(32) | rh rec-bias(32) | ih folded(32)]
    f32x4 BZ0 = *(const f32x4*)(b4 + 0   + 4 * q);
    f32x4 BZ1 = *(const f32x4*)(b4 + 16  + 4 * q);
    f32x4 BR0 = *(const f32x4*)(b4 + 32  + 4 * q);
    f32x4 BR1 = *(const f32x4*)(b4 + 48  + 4 * q);
    f32x4 BH0 = *(const f32x4*)(b4 + 64  + 4 * q);
    f32x4 BH1 = *(const f32x4*)(b4 + 80  + 4 * q);
    f32x4 BI0 = *(const f32x4*)(b4 + 96  + 4 * q);
    f32x4 BI1 = *(const f32x4*)(b4 + 112 + 4 * q);

#define XBASE(s) (((long)(dir ? (Tsz - 2 - (s)) : (1 + (s))) * Bsz + b) * 32)
    {
        long zb = ((long)(dir ? Tsz - 1 : 0) * Bsz + b) * 32;
        float4 z4 = make_float4(0.f, 0.f, 0.f, 0.f);
        *(float4*)(out + zb + 4 * q) = z4;
        *(float4*)(out + zb + 16 + 4 * q) = z4;
    }
    long ob = XBASE(0);
    long ostride = (long)(dir ? -1 : 1) * Bsz * 32;

    // P double-buffer: x-projection results (z,r chained-base; i = ih incl folded bias)
    f32x4 PAz0, PAz1, PAr0, PAr1, PAi0, PAi1;
    f32x4 PBz0, PBz1, PBr0, PBr1, PBi0, PBi1;
    // prologue: P_A for step 0 from x(0)
    {
        long n0 = XBASE(0);
        float4 ta = *(const float4*)(L0 + n0 + 4 * q);
        float4 tb = *(const float4*)(L0 + n0 + 16 + 4 * q);
        float4 tc = *(const float4*)(R0 + n0 + 4 * q);
        float4 td = *(const float4*)(R0 + n0 + 16 + 4 * q);
        H8 Bx = make_B(ta.x + tc.x, ta.y + tc.y, ta.z + tc.z, ta.w + tc.w,
                       tb.x + td.x, tb.y + td.y, tb.z + td.z, tb.w + td.w);
        PAz0 = mfma16(AWz0, Bx, BZ0);
        PAz1 = mfma16(AWz1, Bx, BZ1);
        PAr0 = mfma16(AWr0, Bx, BR0);
        PAr1 = mfma16(AWr1, Bx, BR1);
        PAi0 = mfma16(AWh0, Bx, BI0);
        PAi1 = mfma16(AWh1, Bx, BI1);
    }
    // x slots j=0..3 hold x(1+j); slot used at step s (s%4==j) for Bx(s+1), refilled <- x(s+5)
    float4 la0, lb0, ra0, rb0, la1, lb1, ra1, rb1;
    float4 la2, lb2, ra2, rb2, la3, lb3, ra3, rb3;
    {
        long n1 = XBASE(1);
        la0 = *(const float4*)(L0 + n1 + 4 * q); lb0 = *(const float4*)(L0 + n1 + 16 + 4 * q);
        ra0 = *(const float4*)(R0 + n1 + 4 * q); rb0 = *(const float4*)(R0 + n1 + 16 + 4 * q);
        long n2 = XBASE(2);
        la1 = *(const float4*)(L0 + n2 + 4 * q); lb1 = *(const float4*)(L0 + n2 + 16 + 4 * q);
        ra1 = *(const float4*)(R0 + n2 + 4 * q); rb1 = *(const float4*)(R0 + n2 + 16 + 4 * q);
        long n3 = XBASE(3);
        la2 = *(const float4*)(L0 + n3 + 4 * q); lb2 = *(const float4*)(L0 + n3 + 16 + 4 * q);
        ra2 = *(const float4*)(R0 + n3 + 4 * q); rb2 = *(const float4*)(R0 + n3 + 16 + 4 * q);
        long n4 = XBASE(4);
        la3 = *(const float4*)(L0 + n4 + 4 * q); lb3 = *(const float4*)(L0 + n4 + 16 + 4 * q);
        ra3 = *(const float4*)(R0 + n4 + 4 * q); rb3 = *(const float4*)(R0 + n4 + 16 + 4 * q);
    }
    float h0 = 0.f, h1 = 0.f, h2 = 0.f, h3 = 0.f, h4 = 0.f, h5 = 0.f, h6 = 0.f, h7 = 0.f;

    // step s: consume P (made from x(s)); produce Q (for s+1) from slot = x(s+1); refill slot.
    // Critical path: make_B(h) -> 1 chained MFMA -> gates. Q-production fills hazard window.
#define STEP1(XLA, XLB, XRA, XRB, Pz0, Pz1, Pr0, Pr1, Pi0, Pi1,                \
              Qz0, Qz1, Qr0, Qr1, Qi0, Qi1, SNEXT)                             \
    {                                                                          \
        H8 Bh = make_B(h0, h1, h2, h3, h4, h5, h6, h7);                        \
        f32x4 Cz0 = mfma16(AUz0, Bh, Pz0);                                     \
        f32x4 Cz1 = mfma16(AUz1, Bh, Pz1);                                     \
        f32x4 Cr0 = mfma16(AUr0, Bh, Pr0);                                     \
        f32x4 Cr1 = mfma16(AUr1, Bh, Pr1);                                     \
        f32x4 Ch0 = mfma16(AUh0, Bh, BH0);                                     \
        f32x4 Ch1 = mfma16(AUh1, Bh, BH1);                                     \
        H8 Bx = make_B(XLA.x + XRA.x, XLA.y + XRA.y, XLA.z + XRA.z,            \
                       XLA.w + XRA.w, XLB.x + XRB.x, XLB.y + XRB.y,            \
                       XLB.z + XRB.z, XLB.w + XRB.w);                          \
        Qz0 = mfma16(AWz0, Bx, BZ0);                                           \
        Qz1 = mfma16(AWz1, Bx, BZ1);                                           \
        Qr0 = mfma16(AWr0, Bx, BR0);                                           \
        Qr1 = mfma16(AWr1, Bx, BR1);                                           \
        Qi0 = mfma16(AWh0, Bx, BI0);                                           \
        Qi1 = mfma16(AWh1, Bx, BI1);                                           \
        int sn = (SNEXT); if (sn > Tsz - 2) sn = Tsz - 2;                      \
        long nb = XBASE(sn);                                                   \
        XLA = *(const float4*)(L0 + nb + 4 * q);                               \
        XLB = *(const float4*)(L0 + nb + 16 + 4 * q);                          \
        XRA = *(const float4*)(R0 + nb + 4 * q);                               \
        XRB = *(const float4*)(R0 + nb + 16 + 4 * q);                          \
        h0 = gate1(Cz0.x, Cr0.x, Ch0.x, Pi0.x, h0);                            \
        h1 = gate1(Cz0.y, Cr0.y, Ch0.y, Pi0.y, h1);                            \
        h2 = gate1(Cz0.z, Cr0.z, Ch0.z, Pi0.z, h2);                            \
        h3 = gate1(Cz0.w, Cr0.w, Ch0.w, Pi0.w, h3);                            \
        h4 = gate1(Cz1.x, Cr1.x, Ch1.x, Pi1.x, h4);                            \
        h5 = gate1(Cz1.y, Cr1.y, Ch1.y, Pi1.y, h5);                            \
        h6 = gate1(Cz1.z, Cr1.z, Ch1.z, Pi1.z, h6);                            \
        h7 = gate1(Cz1.w, Cr1.w, Ch1.w, Pi1.w, h7);                            \
        *(float4*)(out + ob + 4 * q) = make_float4(h0, h1, h2, h3);            \
        *(float4*)(out + ob + 16 + 4 * q) = make_float4(h4, h5, h6, h7);       \
        ob += ostride;                                                         \
    }

    for (int sb = 0; sb < 508; sb += 4) {
        STEP1(la0, lb0, ra0, rb0,
              PAz0, PAz1, PAr0, PAr1, PAi0, PAi1,
              PBz0, PBz1, PBr0, PBr1, PBi0, PBi1, sb + 5);
        STEP1(la1, lb1, ra1, rb1,
              PBz0, PBz1, PBr0, PBr1, PBi0, PBi1,
              PAz0, PAz1, PAr0, PAr1, PAi0, PAi1, sb + 6);
        STEP1(la2, lb2, ra2, rb2,
              PAz0, PAz1, PAr0, PAr1, PAi0, PAi1,
              PBz0, PBz1, PBr0, PBr1, PBi0, PBi1, sb + 7);
        STEP1(la3, lb3, ra3, rb3,
              PBz0, PBz1, PBr0, PBr1, PBi0, PBi1,
              PAz0, PAz1, PAr0, PAr1, PAi0, PAi1, sb + 8);
    }
    // tail: steps 508, 509, 510 (Q production + refills are dead/clamped)
    STEP1(la0, lb0, ra0, rb0,
          PAz0, PAz1, PAr0, PAr1, PAi0, PAi1,
          PBz0, PBz1, PBr0, PBr1, PBi0, PBi1, 510);
    STEP1(la1, lb1, ra1, rb1,
          PBz0, PBz1, PBr0, PBr1, PBi0, PBi1,
          PAz0, PAz1, PAr0, PAr1, PAi0, PAi1, 510);
    STEP1(la2, lb2, ra2, rb2,
          PAz0, PAz1, PAr0, PAr1, PAi0, PAi1,
          PBz0, PBz1, PBr0, PBr1, PBi0, PBi1, 510);
#undef STEP1
#undef XBASE
}

// ---------------- K5b: fold layer-1 BN into dense-1 weights ----------------
__global__ __launch_bounds__(256) void lspd_fold2(
    const float* __restrict__ part, const float* __restrict__ g1, const float* __restrict__ be1,
    const float* __restrict__ Wd1, const float* __restrict__ bd1,
    float* __restrict__ Wdp, float* __restrict__ bdp)
{
    __shared__ float sc[32], tc[32];
    int tid = threadIdx.x;
    if (tid < 32) {
        float S = 0.f, Q = 0.f;
        for (int p = 0; p < 128; ++p) { S += part[p * 64 + tid]; Q += part[p * 64 + 32 + tid]; }
        const float invN = 1.0f / 262144.0f;
        float m = S * invN;
        float v = Q * invN - m * m;
        float s = g1[tid] * __builtin_amdgcn_rsqf(v + 1e-3f);
        sc[tid] = s; tc[tid] = be1[tid] - s * m;
    }
    __syncthreads();
    for (int idx = tid; idx < 1024; idx += 256) {
        int k = idx >> 5;
        Wdp[idx] = sc[k] * Wd1[idx];
    }
    if (tid < 32) {
        float acc = bd1[tid];
        for (int k = 0; k < 32; ++k) acc = fmaf(tc[k], Wd1[k * 32 + tid], acc);
        bdp[tid] = acc;
    }
}

// ---------------- K6: dense + per-t batch BN + classifier + softmax; one block per t ----------------
__global__ __launch_bounds__(512) void lspd_final(
    const float* __restrict__ L1a, const float* __restrict__ R1a,
    const float* __restrict__ Wdp, const float* __restrict__ bdp,
    const float* __restrict__ dg, const float* __restrict__ db,
    const float* __restrict__ Wf, const float* __restrict__ bfv,
    float* __restrict__ outp)
{
    __shared__ alignas(16) float sW[1024];
    __shared__ float sb[32], sWf[352], sbf[16], sS[32], sT[32];
    __shared__ float redS[8][32], redQ[8][32];
    int tid = threadIdx.x, t = blockIdx.x;
    for (int i = tid; i < 1024; i += 512) sW[i] = Wdp[i];
    if (tid < 32)  sb[tid] = bdp[tid];
    if (tid < 352) sWf[tid] = Wf[tid];
    if (tid < 11)  sbf[tid] = bfv[tid];
    __syncthreads();

    size_t base = ((size_t)t * Bsz + tid) * 32;
    float xv[32];
#pragma unroll
    for (int c2 = 0; c2 < 32; c2 += 4) {
        float4 a = *(const float4*)(L1a + base + c2);
        float4 b = *(const float4*)(R1a + base + c2);
        xv[c2 + 0] = a.x + b.x; xv[c2 + 1] = a.y + b.y;
        xv[c2 + 2] = a.z + b.z; xv[c2 + 3] = a.w + b.w;
    }
    float o[32];
#pragma unroll
    for (int g = 0; g < 32; ++g) o[g] = sb[g];
#pragma unroll
    for (int k = 0; k < 32; ++k) {
        float xk = xv[k];
#pragma unroll
        for (int g4 = 0; g4 < 8; ++g4) {
            float4 w = *(const float4*)(sW + k * 32 + g4 * 4);   // same-address LDS broadcast
            o[g4 * 4 + 0] = fmaf(xk, w.x, o[g4 * 4 + 0]);
            o[g4 * 4 + 1] = fmaf(xk, w.y, o[g4 * 4 + 1]);
            o[g4 * 4 + 2] = fmaf(xk, w.z, o[g4 * 4 + 2]);
            o[g4 * 4 + 3] = fmaf(xk, w.w, o[g4 * 4 + 3]);
        }
    }
#pragma unroll
    for (int g = 0; g < 32; ++g) o[g] = fmaxf(o[g], 0.f);

    // per-(t,channel) stats over batch (within block)
    int wv = tid >> 6, lane = tid & 63;
    for (int g = 0; g < 32; ++g) {
        float s = o[g], q = o[g] * o[g];
        for (int d = 1; d < 64; d <<= 1) {
            s += __shfl_xor(s, d, 64);
            q += __shfl_xor(q, d, 64);
        }
        if (lane == 0) { redS[wv][g] = s; redQ[wv][g] = q; }
    }
    __syncthreads();
    if (tid < 32) {
        float S = 0.f, Q = 0.f;
        for (int w2 = 0; w2 < 8; ++w2) { S += redS[w2][tid]; Q += redQ[w2][tid]; }
        float m = S * (1.0f / 512.0f);
        float v = Q * (1.0f / 512.0f) - m * m;
        float s = dg[tid] * __builtin_amdgcn_rsqf(v + 1e-3f);
        sS[tid] = s; sT[tid] = db[tid] - s * m;
    }
    __syncthreads();

    float lg[11];
#pragma unroll
    for (int n = 0; n < 11; ++n) lg[n] = sbf[n];
#pragma unroll
    for (int g = 0; g < 32; ++g) {
        float no = fmaf(o[g], sS[g], sT[g]);
#pragma unroll
        for (int n = 0; n < 11; ++n) lg[n] = fmaf(no, sWf[g * 11 + n], lg[n]);
    }
    float mx = lg[0];
#pragma unroll
    for (int n = 1; n < 11; ++n) mx = fmaxf(mx, lg[n]);
    float sum = 0.f;
#pragma unroll
    for (int n = 0; n < 11; ++n) { lg[n] = __expf(lg[n] - mx); sum += lg[n]; }
    float inv = __builtin_amdgcn_rcpf(sum);
    float* op = outp + ((size_t)tid * Tsz + t) * 11;
#pragma unroll
    for (int n = 0; n < 11; ++n) op[n] = lg[n] * inv;
}

extern "C" void kernel_launch(void* const* d_in, const int* in_sizes, int n_in,
                              void* d_out, int out_size, void* d_ws, size_t ws_size,
                              hipStream_t stream)
{
    (void)in_sizes; (void)n_in; (void)out_size; (void)ws_size;
    const float* x   = (const float*)d_in[0];
    const float* emb = (const float*)d_in[1];
    const float* Wl  = (const float*)d_in[2];
    const float* Ul  = (const float*)d_in[3];
    const float* bl  = (const float*)d_in[4];
    const float* Wr  = (const float*)d_in[5];
    const float* Ur  = (const float*)d_in[6];
    const float* br  = (const float*)d_in[7];
    const float* bng = (const float*)d_in[8];
    const float* bnb = (const float*)d_in[9];
    const float* Wd  = (const float*)d_in[10];
    const float* bd  = (const float*)d_in[11];
    const float* dg  = (const float*)d_in[12];
    const float* db  = (const float*)d_in[13];
    const float* Wf  = (const float*)d_in[14];
    const float* bf  = (const float*)d_in[15];
    float* out = (float*)d_out;

    float* ws = (float*)d_ws;
    float* L0 = ws;
    float* R0 = L0 + 8388608;
    float* L1 = R0 + 8388608;
    float* R1 = L1 + 8388608;
    float* rest = R1 + 8388608;
    int* idxT   = (int*)rest;            // 262144 ints
    float* tabL = rest + 262144;
    float* tabR = tabL + 12288;
    float* part1 = tabR + 12288;         // 8192
    float* part2 = part1 + 8192;         // 8192
    float* WpL = part2 + 8192;           // 3072
    float* WpR = WpL + 3072;
    float* b4L = WpR + 3072;             // 128
    float* b4R = b4L + 128;
    float* Wdp = b4R + 128;              // 1024
    float* bdp = Wdp + 1024;             // 32

    lspd_argmax<<<65536, 256, 0, stream>>>(x, idxT);
    lspd_tab<<<96, 256, 0, stream>>>(emb, Wl, bl, Wr, br, tabL, tabR);
    lspd_gru0<<<1024, 64, 0, stream>>>(idxT, tabL, tabR, Ul, Ur, bl, br, L0, R0);
    lspd_stats<<<128, 256, 0, stream>>>(L0, R0, part1);
    lspd_fold1<<<1, 256, 0, stream>>>(part1, bng, bnb, Wl, Wr, bl, br, WpL, WpR, b4L, b4R);
    lspd_gru1<<<64, 64, 0, stream>>>(L0, R0, WpL, WpR, b4L, b4R, Ul + 3072, Ur + 3072, L1, R1);
    lspd_stats<<<128, 256, 0, stream>>>(L1, R1, part2);
    lspd_fold2<<<1, 256, 0, stream>>>(part2, bng + 32, bnb + 32, Wd + 1024, bd + 32, Wdp, bdp);
    lspd_final<<<512, 512, 0, stream>>>(L1, R1, Wdp, bdp, dg + 32, db + 32, Wf, bf, out);
}

// Round 9
// 656.438 us; speedup vs baseline: 2.6014x; 1.0258x over previous
//
#include <hip/hip_runtime.h>

// LSPD_43404939493531: bidirectional 2-layer GRU (B=512,T=512,U=32) + BN folds + dense head.
// R14: feeder-kernel geometry fix. R13 evidence: gru1=215us and NO other kernel in top-5 (so all
//     <215), yet total-gru1 = 458us -> non-GRU kernels sum to >=~245us. Suspects: argmax at
//     65536 blocks x 256thr (one 512B read per wave -> launch/residency-bound, 134MB in 32
//     sequential block-waves) and stats at 128x256 = 0.5 waves/SIMD (no TLP for a BW-bound
//     kernel). Fixes (GRUs untouched for clean A/B):
//       - argmax: 2048 blocks x 256thr grid-stride, each wave loops 32 rows; float2/lane load;
//         same first-occurrence tie-break.
//       - stats: 128 blocks x 1024thr (4x waves/SIMD), same 64-partials-per-block layout so
//         fold kernels and workspace layout are unchanged.
//     gru0 = R7 VALU form; gru1 = R11 MFMA form (both as in R13).

#define Bsz 512
#define Tsz 512

typedef unsigned uintv2 __attribute__((ext_vector_type(2)));
typedef _Float16 half8 __attribute__((ext_vector_type(8)));
typedef float f32x4 __attribute__((ext_vector_type(4)));

union H8 { unsigned u[4]; half8 h; };

__device__ __forceinline__ float sigmoid_f(float x) {
    return __builtin_amdgcn_rcpf(1.0f + __expf(-x));
}

// ---- cross-lane swaps (VALU pipe), two-result form ----
__device__ __forceinline__ uintv2 p16(unsigned a, unsigned b) {
#if __has_builtin(__builtin_amdgcn_permlane16_swap)
    return __builtin_amdgcn_permlane16_swap(a, b, false, false);
#else
    asm("v_permlane16_swap_b32 %0, %1" : "+v"(a), "+v"(b));
    uintv2 r; r.x = a; r.y = b; return r;
#endif
}
__device__ __forceinline__ uintv2 p32(unsigned a, unsigned b) {
#if __has_builtin(__builtin_amdgcn_permlane32_swap)
    return __builtin_amdgcn_permlane32_swap(a, b, false, false);
#else
    asm("v_permlane32_swap_b32 %0, %1" : "+v"(a), "+v"(b));
    uintv2 r; r.x = a; r.y = b; return r;
#endif
}

// ---- R7 VALU-GRU primitives (gru0) ----
__device__ __forceinline__ void plswap16_f(float& a, float& b) {
    uintv2 r = p16(__float_as_uint(a), __float_as_uint(b));
    a = __uint_as_float(r.x);
    b = __uint_as_float(r.y);
}
__device__ __forceinline__ void plswap16_i(int& a, int& b) {
    uintv2 r = p16((unsigned)a, (unsigned)b);
    a = (int)r.x;
    b = (int)r.y;
}
__device__ __forceinline__ float xhalfsum(float a) {   // a[lane] + a[lane^32]
    uintv2 r = p32(__float_as_uint(a), __float_as_uint(a));
    return __uint_as_float(r.x) + __uint_as_float(r.y);
}

// DPP row_newbcast:n (ctrl 0x150+n): broadcast in-row lane n to the whole 16-lane row
#define NB_F(d, s, n) d = __int_as_float(__builtin_amdgcn_update_dpp(0, __float_as_int(s), 0x150 + n, 0xF, 0xF, true))
#define NB_I(d, s, n) d = __builtin_amdgcn_update_dpp(0, (s), 0x150 + n, 0xF, 0xF, true)
#define BCAST16F(A, S)                                                         \
    NB_F(A[0], S, 0);  NB_F(A[1], S, 1);  NB_F(A[2], S, 2);  NB_F(A[3], S, 3); \
    NB_F(A[4], S, 4);  NB_F(A[5], S, 5);  NB_F(A[6], S, 6);  NB_F(A[7], S, 7); \
    NB_F(A[8], S, 8);  NB_F(A[9], S, 9);  NB_F(A[10], S, 10); NB_F(A[11], S, 11); \
    NB_F(A[12], S, 12); NB_F(A[13], S, 13); NB_F(A[14], S, 14); NB_F(A[15], S, 15)
#define BCAST16I(A, S)                                                         \
    NB_I(A[0], S, 0);  NB_I(A[1], S, 1);  NB_I(A[2], S, 2);  NB_I(A[3], S, 3); \
    NB_I(A[4], S, 4);  NB_I(A[5], S, 5);  NB_I(A[6], S, 6);  NB_I(A[7], S, 7); \
    NB_I(A[8], S, 8);  NB_I(A[9], S, 9);  NB_I(A[10], S, 10); NB_I(A[11], S, 11); \
    NB_I(A[12], S, 12); NB_I(A[13], S, 13); NB_I(A[14], S, 14); NB_I(A[15], S, 15)

// ---- R11 MFMA-GRU primitives (gru1) ----
// Fixed routing network: 4 packed words (2 ch each, C-layout) -> 4 B-fragment words.
__device__ __forceinline__ void route4(unsigned P0, unsigned P1, unsigned P2, unsigned P3,
                                       unsigned& W0, unsigned& W1, unsigned& W2, unsigned& W3)
{
    uintv2 m = p32(P0, P2);
    uintv2 a = p16(m.x, m.y);
    uintv2 n = p32(P1, P3);
    uintv2 c = p16(n.x, n.y);
    W0 = a.x; W2 = a.y; W1 = c.x; W3 = c.y;
}

__device__ __forceinline__ unsigned pk16(float a, float b) {
    auto h = __builtin_amdgcn_cvt_pkrtz(a, b);   // __fp16 ext_vector_type(2)
    return __builtin_bit_cast(unsigned, h);
}

__device__ __forceinline__ H8 make_B(float v0, float v1, float v2, float v3,
                                     float v4, float v5, float v6, float v7)
{
    unsigned P0 = pk16(v0, v1), P1 = pk16(v2, v3);
    unsigned P2 = pk16(v4, v5), P3 = pk16(v6, v7);
    H8 b;
    route4(P0, P1, P2, P3, b.u[0], b.u[1], b.u[2], b.u[3]);
    return b;
}

// calibrate: cs[e] = channel whose value lands in B-slot e for this lane
__device__ __forceinline__ void calib_slots(int lane, int cs[8]) {
    unsigned q = (unsigned)(lane >> 4) & 3u;
    unsigned c0 = 4u * q, c1 = 16u + 4u * q;
    unsigned P0 = c0 | ((c0 + 1u) << 16);
    unsigned P1 = (c0 + 2u) | ((c0 + 3u) << 16);
    unsigned P2 = c1 | ((c1 + 1u) << 16);
    unsigned P3 = (c1 + 2u) | ((c1 + 3u) << 16);
    unsigned W0, W1, W2, W3;
    route4(P0, P1, P2, P3, W0, W1, W2, W3);
    cs[0] = W0 & 0xffff; cs[1] = W0 >> 16;
    cs[2] = W1 & 0xffff; cs[3] = W1 >> 16;
    cs[4] = W2 & 0xffff; cs[5] = W2 >> 16;
    cs[6] = W3 & 0xffff; cs[7] = W3 >> 16;
}

// A-tile: row = lane&15 (gate row within tile), slot e multiplies B slot e -> load via cs[]
__device__ __forceinline__ H8 load_A(const float* __restrict__ M, const int cs[8], int gcol) {
    H8 a;
#pragma unroll
    for (int e = 0; e < 4; ++e)
        a.u[e] = pk16(M[cs[2 * e] * 96 + gcol], M[cs[2 * e + 1] * 96 + gcol]);
    return a;
}

__device__ __forceinline__ f32x4 mfma16(const H8& a, const H8& b, f32x4 c) {
    return __builtin_amdgcn_mfma_f32_16x16x32_f16(a.h, b.h, c, 0, 0, 0);
}

__device__ __forceinline__ float gate1(float az, float ar, float ah, float ai, float h) {
    float z = sigmoid_f(az);
    float r = sigmoid_f(ar);
    float hh = fmaxf(0.f, fmaf(r, ah, ai));
    return hh + z * (h - hh);
}

// ---------------- K1: argmax over D=128, grid-stride, one wave per row, 32 rows/wave ----------------
__global__ __launch_bounds__(256) void lspd_argmax(const float* __restrict__ x, int* __restrict__ idxT)
{
    int wv = threadIdx.x >> 6, lane = threadIdx.x & 63;
    int wave_id = blockIdx.x * 4 + wv;            // 0..8191
    for (int r = 0; r < 32; ++r) {
        long p = (long)wave_id + (long)r * 8192;  // p = b*512 + t, all 262144 rows covered
        const float* xp = x + p * 128;
        float2 a = *(const float2*)(xp + 2 * lane);
        float v0 = a.x; int i0 = 2 * lane;
        if (a.y > v0) { v0 = a.y; i0 = 2 * lane + 1; }   // ties keep lower index
#pragma unroll
        for (int d = 1; d < 64; d <<= 1) {
            float ov = __shfl_xor(v0, d, 64);
            int   oi = __shfl_xor(i0, d, 64);
            if (ov > v0 || (ov == v0 && oi < i0)) { v0 = ov; i0 = oi; }
        }
        if (lane == 0) idxT[p] = i0;
    }
}

// ---------------- K0: layer-0 input tables tab[i][g] = (emb@W0)[i][g] + b0_in[g] ----------------
__global__ __launch_bounds__(256) void lspd_tab(
    const float* __restrict__ emb, const float* __restrict__ Wl, const float* __restrict__ bl,
    const float* __restrict__ Wr, const float* __restrict__ br,
    float* __restrict__ tabL, float* __restrict__ tabR)
{
    int flat = blockIdx.x * 256 + threadIdx.x;    // 0..24575
    int dir = flat / 12288;
    int r = flat % 12288;
    int i = r / 96, g = r % 96;
    const float* W  = dir ? Wr : Wl;              // layer 0 at base
    const float* bb = dir ? br : bl;              // b[0][0] input bias at base
    float acc = bb[g];
#pragma unroll
    for (int k = 0; k < 32; ++k) acc = fmaf(emb[i * 32 + k], W[k * 96 + g], acc);
    (dir ? tabR : tabL)[r] = acc;
}

// ---------------- K2: layer-0 GRU (R7 VALU form), 1 chain per wave, 1024 waves ----------------
__global__ __launch_bounds__(64)
__attribute__((amdgpu_waves_per_eu(1, 1)))
void lspd_gru0(
    const int* __restrict__ idxT, const float* __restrict__ tabL, const float* __restrict__ tabR,
    const float* __restrict__ Ul, const float* __restrict__ Ur,
    const float* __restrict__ bl, const float* __restrict__ br,
    float* __restrict__ Lout, float* __restrict__ Rout)
{
    int wid = blockIdx.x;
    int dir = wid >> 9;
    int b = wid & 511;
    int lane = threadIdx.x;
    int half = lane >> 5, c = lane & 31;
    const float* U    = dir ? Ur : Ul;
    const float* tab  = dir ? tabR : tabL;
    const float* brec = (dir ? br : bl) + 96;     // layer-0 recurrent bias b[0][1]
    float* out        = dir ? Rout : Lout;

    // ---- permutation self-calibration: kk[j] = channel whose h lands in hk[j] ----
    int ksA = c, ksB = c;
    plswap16_i(ksA, ksB);
    bool selA = ((ksA >> 4) == half);
    int ksel = selA ? ksA : ksB;
    int kk[16];
    BCAST16I(kk, ksel);

    float u0[16], u1[16], u2[16];
#pragma unroll
    for (int j = 0; j < 16; ++j) {
        u0[j] = U[kk[j] * 96 + c];
        u1[j] = U[kk[j] * 96 + 32 + c];
        u2[j] = U[kk[j] * 96 + 64 + c];
    }
    float bZ = half ? 0.f : brec[c];
    float bR = half ? 0.f : brec[32 + c];
    float bH = half ? 0.f : brec[64 + c];
#pragma unroll
    for (int j = 0; j < 16; ++j) {
        asm volatile("" : "+v"(u0[j]), "+v"(u1[j]), "+v"(u2[j]));
    }
    asm volatile("" : "+v"(bZ), "+v"(bR), "+v"(bH));

    const int* idxrow = idxT + (long)b * Tsz;
    if (lane < 32) out[(((long)(dir ? Tsz - 1 : 0)) * Bsz + b) * 32 + c] = 0.f;  // boundary zero

#define TT0(s) (dir ? (Tsz - 2 - (s)) : (1 + (s)))
    long ob = ((long)TT0(0) * Bsz + b) * 32 + c;
    long ostride = (long)(dir ? -1 : 1) * Bsz * 32;

    // 4-slot gi pipeline (gather 4 steps ahead), idx 8 ahead
    float g0z, g0r, g0h, g1z, g1r, g1h, g2z, g2r, g2h, g3z, g3r, g3h;
    { int i = idxrow[TT0(0)]; g0z = tab[i * 96 + c]; g0r = tab[i * 96 + 32 + c]; g0h = tab[i * 96 + 64 + c]; }
    { int i = idxrow[TT0(1)]; g1z = tab[i * 96 + c]; g1r = tab[i * 96 + 32 + c]; g1h = tab[i * 96 + 64 + c]; }
    { int i = idxrow[TT0(2)]; g2z = tab[i * 96 + c]; g2r = tab[i * 96 + 32 + c]; g2h = tab[i * 96 + 64 + c]; }
    { int i = idxrow[TT0(3)]; g3z = tab[i * 96 + c]; g3r = tab[i * 96 + 32 + c]; g3h = tab[i * 96 + 64 + c]; }
    int i0 = idxrow[TT0(4)];
    int i1 = idxrow[TT0(5)];
    int i2 = idxrow[TT0(6)];
    int i3 = idxrow[TT0(7)];
    float h = 0.f;

#define GSTEP(GZ, GR, GH, IREG, SNEXT)                                         \
    {                                                                          \
        float ha = h, hb = h;                                                  \
        plswap16_f(ha, hb);                                                    \
        float hs = selA ? ha : hb;                                             \
        float hk[16];                                                          \
        BCAST16F(hk, hs);                                                      \
        float az = bZ, ar = bR, ah = bH;                                       \
        _Pragma("unroll")                                                      \
        for (int n = 0; n < 16; ++n) {                                         \
            az = fmaf(hk[n], u0[n], az);                                       \
            ar = fmaf(hk[n], u1[n], ar);                                       \
            ah = fmaf(hk[n], u2[n], ah);                                       \
        }                                                                      \
        az = xhalfsum(az); ar = xhalfsum(ar); ah = xhalfsum(ah);               \
        float z = sigmoid_f(az + GZ);                                          \
        float r = sigmoid_f(ar + GR);                                          \
        float hh = fmaxf(0.f, fmaf(r, ah, GH));                                \
        h = hh + z * (h - hh);                                                 \
        if (lane < 32) out[ob] = h;                                            \
        ob += ostride;                                                         \
        GZ = tab[IREG * 96 + c];                                               \
        GR = tab[IREG * 96 + 32 + c];                                          \
        GH = tab[IREG * 96 + 64 + c];                                          \
        int sn = (SNEXT); if (sn > Tsz - 2) sn = Tsz - 2;                      \
        IREG = idxrow[TT0(sn)];                                                \
    }

    for (int sb = 0; sb < 508; sb += 4) {
        GSTEP(g0z, g0r, g0h, i0, sb + 8);
        GSTEP(g1z, g1r, g1h, i1, sb + 9);
        GSTEP(g2z, g2r, g2h, i2, sb + 10);
        GSTEP(g3z, g3r, g3h, i3, sb + 11);
    }
    // tail: steps 508, 509, 510 (refills are clamped duplicates, dead)
    GSTEP(g0z, g0r, g0h, i0, 510);
    GSTEP(g1z, g1r, g1h, i1, 510);
    GSTEP(g2z, g2r, g2h, i2, 510);
#undef GSTEP
#undef TT0
}

// ---------------- K3/K5: per-channel sum & sumsq of (L+R), 1024 threads for TLP ----------------
__global__ __launch_bounds__(1024) void lspd_stats(
    const float* __restrict__ A, const float* __restrict__ Bv, float* __restrict__ part)
{
    __shared__ float sS[1024], sQ[1024];
    int tid = threadIdx.x;
    size_t base = (size_t)blockIdx.x * 65536 + tid;
    float s = 0.f, q = 0.f;
    for (int i = 0; i < 64; ++i) {
        size_t ix = base + (size_t)i * 1024;
        float v = A[ix] + Bv[ix];
        s += v; q = fmaf(v, v, q);
    }
    sS[tid] = s; sQ[tid] = q;
    __syncthreads();
    if (tid < 32) {
        float S = 0.f, Q = 0.f;
        for (int j = 0; j < 32; ++j) { S += sS[tid + 32 * j]; Q += sQ[tid + 32 * j]; }
        part[blockIdx.x * 64 + tid] = S;
        part[blockIdx.x * 64 + 32 + tid] = Q;
    }
}

// ---------------- K3b: fold layer-0 BN into layer-1 input weights ----------------
__global__ __launch_bounds__(256) void lspd_fold1(
    const float* __restrict__ part, const float* __restrict__ g0, const float* __restrict__ be0,
    const float* __restrict__ Wl, const float* __restrict__ Wr,
    const float* __restrict__ bl, const float* __restrict__ br,
    float* __restrict__ WpL, float* __restrict__ WpR,
    float* __restrict__ b4L, float* __restrict__ b4R)
{
    __shared__ float sc[32], tc[32];
    int tid = threadIdx.x;
    if (tid < 32) {
        float S = 0.f, Q = 0.f;
        for (int p = 0; p < 128; ++p) { S += part[p * 64 + tid]; Q += part[p * 64 + 32 + tid]; }
        const float invN = 1.0f / 262144.0f;
        float m = S * invN;
        float v = Q * invN - m * m;
        float s = g0[tid] * __builtin_amdgcn_rsqf(v + 1e-3f);
        sc[tid] = s; tc[tid] = be0[tid] - s * m;
    }
    __syncthreads();
    for (int idx = tid; idx < 6144; idx += 256) {
        int dir = idx / 3072, e = idx % 3072, k = e / 96, g = e % 96;
        const float* W1 = (dir ? Wr : Wl) + 3072;      // layer 1
        (dir ? WpR : WpL)[e] = sc[k] * W1[k * 96 + g];
    }
    {
        int idx = tid;                                  // 256 entries exactly
        int dir = idx >> 7, slot = idx & 127, sub = slot >> 5, cc = slot & 31;
        const float* bb = (dir ? br : bl) + 192;        // layer-1: [0..95]=input, [96..191]=recurrent
        const float* W1 = (dir ? Wr : Wl) + 3072;
        float r;
        if (sub == 2) {
            r = bb[96 + 64 + cc];                       // rh: recurrent h-bias only
        } else {
            int g = (sub == 3) ? (64 + cc) : (sub * 32 + cc);
            float acc = bb[g];                          // input bias
            for (int k = 0; k < 32; ++k) acc = fmaf(tc[k], W1[k * 96 + g], acc);
            if (sub < 2) acc += bb[96 + g];             // z,r: + recurrent bias
            r = acc;
        }
        (dir ? b4R : b4L)[slot] = r;
    }
}

// ---------------- K4: layer-1 GRU (R11 MFMA form), 16 batch rows per wave, 64 waves ----------------
__global__ __launch_bounds__(64)
__attribute__((amdgpu_waves_per_eu(1, 1)))
void lspd_gru1(
    const float* __restrict__ L0, const float* __restrict__ R0,
    const float* __restrict__ WpL, const float* __restrict__ WpR,
    const float* __restrict__ b4L, const float* __restrict__ b4R,
    const float* __restrict__ Ul1, const float* __restrict__ Ur1,
    float* __restrict__ Lout, float* __restrict__ Rout)
{
    int bid = blockIdx.x;
    int dir = bid >> 5;
    int bg  = bid & 31;
    int lane = threadIdx.x;
    int rl = lane & 15;
    int q  = lane >> 4;
    int b  = bg * 16 + rl;
    const float* U  = dir ? Ur1 : Ul1;
    const float* Wp = dir ? WpR : WpL;
    const float* b4 = dir ? b4R : b4L;
    float* out      = dir ? Rout : Lout;

    int cs[8];
    calib_slots(lane, cs);

    H8 AWz0 = load_A(Wp, cs, 0  + rl), AWz1 = load_A(Wp, cs, 16 + rl);
    H8 AWr0 = load_A(Wp, cs, 32 + rl), AWr1 = load_A(Wp, cs, 48 + rl);
    H8 AWh0 = load_A(Wp, cs, 64 + rl), AWh1 = load_A(Wp, cs, 80 + rl);
    H8 AUz0 = load_A(U, cs, 0  + rl),  AUz1 = load_A(U, cs, 16 + rl);
    H8 AUr0 = load_A(U, cs, 32 + rl),  AUr1 = load_A(U, cs, 48 + rl);
    H8 AUh0 = load_A(U, cs, 64 + rl),  AUh1 = load_A(U, cs, 80 + rl);
    // bias fragments: b4 = [z total(32) | r total(32) | rh rec-bias(32) | ih folded(32)]
    f32x4 BZ0 = *(const f32x4*)(b4 + 0   + 4 * q);
    f32x4 BZ1 = *(const f32x4*)(b4 + 16  + 4 * q);
    f32x4 BR0 = *(const f32x4*)(b4 + 32  + 4 * q);
    f32x4 BR1 = *(const f32x4*)(b4 + 48  + 4 * q);
    f32x4 BH0 = *(const f32x4*)(b4 + 64  + 4 * q);
    f32x4 BH1 = *(const f32x4*)(b4 + 80  + 4 * q);
    f32x4 BI0 = *(const f32x4*)(b4 + 96  + 4 * q);
    f32x4 BI1 = *(const f32x4*)(b4 + 112 + 4 * q);

#define XBASE(s) (((long)(dir ? (Tsz - 2 - (s)) : (1 + (s))) * Bsz + b) * 32)
    {
        long zb = ((long)(dir ? Tsz - 1 : 0) * Bsz + b) * 32;
        float4 z4 = make_float4(0.f, 0.f, 0.f, 0.f);
        *(float4*)(out + zb + 4 * q) = z4;
        *(float4*)(out + zb + 16 + 4 * q) = z4;
    }
    long ob = XBASE(0);
    long ostride = (long)(dir ? -1 : 1) * Bsz * 32;

    // P double-buffer: x-projection results (z,r chained-base; i = ih incl folded bias)
    f32x4 PAz0, PAz1, PAr0, PAr1, PAi0, PAi1;
    f32x4 PBz0, PBz1, PBr0, PBr1, PBi0, PBi1;
    // prologue: P_A for step 0 from x(0)
    {
        long n0 = XBASE(0);
        float4 ta = *(const float4*)(L0 + n0 + 4 * q);
        float4 tb = *(const float4*)(L0 + n0 + 16 + 4 * q);
        float4 tc = *(const float4*)(R0 + n0 + 4 * q);
        float4 td = *(const float4*)(R0 + n0 + 16 + 4 * q);
        H8 Bx = make_B(ta.x + tc.x, ta.y + tc.y, ta.z + tc.z, ta.w + tc.w,
                       tb.x + td.x, tb.y + td.y, tb.z + td.z, tb.w + td.w);
        PAz0 = mfma16(AWz0, Bx, BZ0);
        PAz1 = mfma16(AWz1, Bx, BZ1);
        PAr0 = mfma16(AWr0, Bx, BR0);
        PAr1 = mfma16(AWr1, Bx, BR1);
        PAi0 = mfma16(AWh0, Bx, BI0);
        PAi1 = mfma16(AWh1, Bx, BI1);
    }
    // x slots j=0..3 hold x(1+j); slot used at step s (s%4==j) for Bx(s+1), refilled <- x(s+5)
    float4 la0, lb0, ra0, rb0, la1, lb1, ra1, rb1;
    float4 la2, lb2, ra2, rb2, la3, lb3, ra3, rb3;
    {
        long n1 = XBASE(1);
        la0 = *(const float4*)(L0 + n1 + 4 * q); lb0 = *(const float4*)(L0 + n1 + 16 + 4 * q);
        ra0 = *(const float4*)(R0 + n1 + 4 * q); rb0 = *(const float4*)(R0 + n1 + 16 + 4 * q);
        long n2 = XBASE(2);
        la1 = *(const float4*)(L0 + n2 + 4 * q); lb1 = *(const float4*)(L0 + n2 + 16 + 4 * q);
        ra1 = *(const float4*)(R0 + n2 + 4 * q); rb1 = *(const float4*)(R0 + n2 + 16 + 4 * q);
        long n3 = XBASE(3);
        la2 = *(const float4*)(L0 + n3 + 4 * q); lb2 = *(const float4*)(L0 + n3 + 16 + 4 * q);
        ra2 = *(const float4*)(R0 + n3 + 4 * q); rb2 = *(const float4*)(R0 + n3 + 16 + 4 * q);
        long n4 = XBASE(4);
        la3 = *(const float4*)(L0 + n4 + 4 * q); lb3 = *(const float4*)(L0 + n4 + 16 + 4 * q);
        ra3 = *(const float4*)(R0 + n4 + 4 * q); rb3 = *(const float4*)(R0 + n4 + 16 + 4 * q);
    }
    float h0 = 0.f, h1 = 0.f, h2 = 0.f, h3 = 0.f, h4 = 0.f, h5 = 0.f, h6 = 0.f, h7 = 0.f;

    // step s: consume P (made from x(s)); produce Q (for s+1) from slot = x(s+1); refill slot.
    // Critical path: make_B(h) -> 1 chained MFMA -> gates. Q-production fills hazard window.
#define STEP1(XLA, XLB, XRA, XRB, Pz0, Pz1, Pr0, Pr1, Pi0, Pi1,                \
              Qz0, Qz1, Qr0, Qr1, Qi0, Qi1, SNEXT)                             \
    {                                                                          \
        H8 Bh = make_B(h0, h1, h2, h3, h4, h5, h6, h7);                        \
        f32x4 Cz0 = mfma16(AUz0, Bh, Pz0);                                     \
        f32x4 Cz1 = mfma16(AUz1, Bh, Pz1);                                     \
        f32x4 Cr0 = mfma16(AUr0, Bh, Pr0);                                     \
        f32x4 Cr1 = mfma16(AUr1, Bh, Pr1);                                     \
        f32x4 Ch0 = mfma16(AUh0, Bh, BH0);                                     \
        f32x4 Ch1 = mfma16(AUh1, Bh, BH1);                                     \
        H8 Bx = make_B(XLA.x + XRA.x, XLA.y + XRA.y, XLA.z + XRA.z,            \
                       XLA.w + XRA.w, XLB.x + XRB.x, XLB.y + XRB.y,            \
                       XLB.z + XRB.z, XLB.w + XRB.w);                          \
        Qz0 = mfma16(AWz0, Bx, BZ0);                                           \
        Qz1 = mfma16(AWz1, Bx, BZ1);                                           \
        Qr0 = mfma16(AWr0, Bx, BR0);                                           \
        Qr1 = mfma16(AWr1, Bx, BR1);                                           \
        Qi0 = mfma16(AWh0, Bx, BI0);                                           \
        Qi1 = mfma16(AWh1, Bx, BI1);                                           \
        int sn = (SNEXT); if (sn > Tsz - 2) sn = Tsz - 2;                      \
        long nb = XBASE(sn);                                                   \
        XLA = *(const float4*)(L0 + nb + 4 * q);                               \
        XLB = *(const float4*)(L0 + nb + 16 + 4 * q);                          \
        XRA = *(const float4*)(R0 + nb + 4 * q);                               \
        XRB = *(const float4*)(R0 + nb + 16 + 4 * q);                          \
        h0 = gate1(Cz0.x, Cr0.x, Ch0.x, Pi0.x, h0);                            \
        h1 = gate1(Cz0.y, Cr0.y, Ch0.y, Pi0.y, h1);                            \
        h2 = gate1(Cz0.z, Cr0.z, Ch0.z, Pi0.z, h2);                            \
        h3 = gate1(Cz0.w, Cr0.w, Ch0.w, Pi0.w, h3);                            \
        h4 = gate1(Cz1.x, Cr1.x, Ch1.x, Pi1.x, h4);                            \
        h5 = gate1(Cz1.y, Cr1.y, Ch1.y, Pi1.y, h5);                            \
        h6 = gate1(Cz1.z, Cr1.z, Ch1.z, Pi1.z, h6);                            \
        h7 = gate1(Cz1.w, Cr1.w, Ch1.w, Pi1.w, h7);                            \
        *(float4*)(out + ob + 4 * q) = make_float4(h0, h1, h2, h3);            \
        *(float4*)(out + ob + 16 + 4 * q) = make_float4(h4, h5, h6, h7);       \
        ob += ostride;                                                         \
    }

    for (int sb = 0; sb < 508; sb += 4) {
        STEP1(la0, lb0, ra0, rb0,
              PAz0, PAz1, PAr0, PAr1, PAi0, PAi1,
              PBz0, PBz1, PBr0, PBr1, PBi0, PBi1, sb + 5);
        STEP1(la1, lb1, ra1, rb1,
              PBz0, PBz1, PBr0, PBr1, PBi0, PBi1,
              PAz0, PAz1, PAr0, PAr1, PAi0, PAi1, sb + 6);
        STEP1(la2, lb2, ra2, rb2,
              PAz0, PAz1, PAr0, PAr1, PAi0, PAi1,
              PBz0, PBz1, PBr0, PBr1, PBi0, PBi1, sb + 7);
        STEP1(la3, lb3, ra3, rb3,
              PBz0, PBz1, PBr0, PBr1, PBi0, PBi1,
              PAz0, PAz1, PAr0, PAr1, PAi0, PAi1, sb + 8);
    }
    // tail: steps 508, 509, 510 (Q production + refills are dead/clamped)
    STEP1(la0, lb0, ra0, rb0,
          PAz0, PAz1, PAr0, PAr1, PAi0, PAi1,
          PBz0, PBz1, PBr0, PBr1, PBi0, PBi1, 510);
    STEP1(la1, lb1, ra1, rb1,
          PBz0, PBz1, PBr0, PBr1, PBi0, PBi1,
          PAz0, PAz1, PAr0, PAr1, PAi0, PAi1, 510);
    STEP1(la2, lb2, ra2, rb2,
          PAz0, PAz1, PAr0, PAr1, PAi0, PAi1,
          PBz0, PBz1, PBr0, PBr1, PBi0, PBi1, 510);
#undef STEP1
#undef XBASE
}

// ---------------- K5b: fold layer-1 BN into dense-1 weights ----------------
__global__ __launch_bounds__(256) void lspd_fold2(
    const float* __restrict__ part, const float* __restrict__ g1, const float* __restrict__ be1,
    const float* __restrict__ Wd1, const float* __restrict__ bd1,
    float* __restrict__ Wdp, float* __restrict__ bdp)
{
    __shared__ float sc[32], tc[32];
    int tid = threadIdx.x;
    if (tid < 32) {
        float S = 0.f, Q = 0.f;
        for (int p = 0; p < 128; ++p) { S += part[p * 64 + tid]; Q += part[p * 64 + 32 + tid]; }
        const float invN = 1.0f / 262144.0f;
        float m = S * invN;
        float v = Q * invN - m * m;
        float s = g1[tid] * __builtin_amdgcn_rsqf(v + 1e-3f);
        sc[tid] = s; tc[tid] = be1[tid] - s * m;
    }
    __syncthreads();
    for (int idx = tid; idx < 1024; idx += 256) {
        int k = idx >> 5;
        Wdp[idx] = sc[k] * Wd1[idx];
    }
    if (tid < 32) {
        float acc = bd1[tid];
        for (int k = 0; k < 32; ++k) acc = fmaf(tc[k], Wd1[k * 32 + tid], acc);
        bdp[tid] = acc;
    }
}

// ---------------- K6: dense + per-t batch BN + classifier + softmax; one block per t ----------------
__global__ __launch_bounds__(512) void lspd_final(
    const float* __restrict__ L1a, const float* __restrict__ R1a,
    const float* __restrict__ Wdp, const float* __restrict__ bdp,
    const float* __restrict__ dg, const float* __restrict__ db,
    const float* __restrict__ Wf, const float* __restrict__ bfv,
    float* __restrict__ outp)
{
    __shared__ alignas(16) float sW[1024];
    __shared__ float sb[32], sWf[352], sbf[16], sS[32], sT[32];
    __shared__ float redS[8][32], redQ[8][32];
    int tid = threadIdx.x, t = blockIdx.x;
    for (int i = tid; i < 1024; i += 512) sW[i] = Wdp[i];
    if (tid < 32)  sb[tid] = bdp[tid];
    if (tid < 352) sWf[tid] = Wf[tid];
    if (tid < 11)  sbf[tid] = bfv[tid];
    __syncthreads();

    size_t base = ((size_t)t * Bsz + tid) * 32;
    float xv[32];
#pragma unroll
    for (int c2 = 0; c2 < 32; c2 += 4) {
        float4 a = *(const float4*)(L1a + base + c2);
        float4 b = *(const float4*)(R1a + base + c2);
        xv[c2 + 0] = a.x + b.x; xv[c2 + 1] = a.y + b.y;
        xv[c2 + 2] = a.z + b.z; xv[c2 + 3] = a.w + b.w;
    }
    float o[32];
#pragma unroll
    for (int g = 0; g < 32; ++g) o[g] = sb[g];
#pragma unroll
    for (int k = 0; k < 32; ++k) {
        float xk = xv[k];
#pragma unroll
        for (int g4 = 0; g4 < 8; ++g4) {
            float4 w = *(const float4*)(sW + k * 32 + g4 * 4);   // same-address LDS broadcast
            o[g4 * 4 + 0] = fmaf(xk, w.x, o[g4 * 4 + 0]);
            o[g4 * 4 + 1] = fmaf(xk, w.y, o[g4 * 4 + 1]);
            o[g4 * 4 + 2] = fmaf(xk, w.z, o[g4 * 4 + 2]);
            o[g4 * 4 + 3] = fmaf(xk, w.w, o[g4 * 4 + 3]);
        }
    }
#pragma unroll
    for (int g = 0; g < 32; ++g) o[g] = fmaxf(o[g], 0.f);

    // per-(t,channel) stats over batch (within block)
    int wv = tid >> 6, lane = tid & 63;
    for (int g = 0; g < 32; ++g) {
        float s = o[g], q = o[g] * o[g];
        for (int d = 1; d < 64; d <<= 1) {
            s += __shfl_xor(s, d, 64);
            q += __shfl_xor(q, d, 64);
        }
        if (lane == 0) { redS[wv][g] = s; redQ[wv][g] = q; }
    }
    __syncthreads();
    if (tid < 32) {
        float S = 0.f, Q = 0.f;
        for (int w2 = 0; w2 < 8; ++w2) { S += redS[w2][tid]; Q += redQ[w2][tid]; }
        float m = S * (1.0f / 512.0f);
        float v = Q * (1.0f / 512.0f) - m * m;
        float s = dg[tid] * __builtin_amdgcn_rsqf(v + 1e-3f);
        sS[tid] = s; sT[tid] = db[tid] - s * m;
    }
    __syncthreads();

    float lg[11];
#pragma unroll
    for (int n = 0; n < 11; ++n) lg[n] = sbf[n];
#pragma unroll
    for (int g = 0; g < 32; ++g) {
        float no = fmaf(o[g], sS[g], sT[g]);
#pragma unroll
        for (int n = 0; n < 11; ++n) lg[n] = fmaf(no, sWf[g * 11 + n], lg[n]);
    }
    float mx = lg[0];
#pragma unroll
    for (int n = 1; n < 11; ++n) mx = fmaxf(mx, lg[n]);
    float sum = 0.f;
#pragma unroll
    for (int n = 0; n < 11; ++n) { lg[n] = __expf(lg[n] - mx); sum += lg[n]; }
    float inv = __builtin_amdgcn_rcpf(sum);
    float* op = outp + ((size_t)tid * Tsz + t) * 11;
#pragma unroll
    for (int n = 0; n < 11; ++n) op[n] = lg[n] * inv;
}

extern "C" void kernel_launch(void* const* d_in, const int* in_sizes, int n_in,
                              void* d_out, int out_size, void* d_ws, size_t ws_size,
                              hipStream_t stream)
{
    (void)in_sizes; (void)n_in; (void)out_size; (void)ws_size;
    const float* x   = (const float*)d_in[0];
    const float* emb = (const float*)d_in[1];
    const float* Wl  = (const float*)d_in[2];
    const float* Ul  = (const float*)d_in[3];
    const float* bl  = (const float*)d_in[4];
    const float* Wr  = (const float*)d_in[5];
    const float* Ur  = (const float*)d_in[6];
    const float* br  = (const float*)d_in[7];
    const float* bng = (const float*)d_in[8];
    const float* bnb = (const float*)d_in[9];
    const float* Wd  = (const float*)d_in[10];
    const float* bd  = (const float*)d_in[11];
    const float* dg  = (const float*)d_in[12];
    const float* db  = (const float*)d_in[13];
    const float* Wf  = (const float*)d_in[14];
    const float* bf  = (const float*)d_in[15];
    float* out = (float*)d_out;

    float* ws = (float*)d_ws;
    float* L0 = ws;
    float* R0 = L0 + 8388608;
    float* L1 = R0 + 8388608;
    float* R1 = L1 + 8388608;
    float* rest = R1 + 8388608;
    int* idxT   = (int*)rest;            // 262144 ints
    float* tabL = rest + 262144;
    float* tabR = tabL + 12288;
    float* part1 = tabR + 12288;         // 8192
    float* part2 = part1 + 8192;         // 8192
    float* WpL = part2 + 8192;           // 3072
    float* WpR = WpL + 3072;
    float* b4L = WpR + 3072;             // 128
    float* b4R = b4L + 128;
    float* Wdp = b4R + 128;              // 1024
    float* bdp = Wdp + 1024;             // 32

    lspd_argmax<<<2048, 256, 0, stream>>>(x, idxT);
    lspd_tab<<<96, 256, 0, stream>>>(emb, Wl, bl, Wr, br, tabL, tabR);
    lspd_gru0<<<1024, 64, 0, stream>>>(idxT, tabL, tabR, Ul, Ur, bl, br, L0, R0);
    lspd_stats<<<128, 1024, 0, stream>>>(L0, R0, part1);
    lspd_fold1<<<1, 256, 0, stream>>>(part1, bng, bnb, Wl, Wr, bl, br, WpL, WpR, b4L, b4R);
    lspd_gru1<<<64, 64, 0, stream>>>(L0, R0, WpL, WpR, b4L, b4R, Ul + 3072, Ur + 3072, L1, R1);
    lspd_stats<<<128, 1024, 0, stream>>>(L1, R1, part2);
    lspd_fold2<<<1, 256, 0, stream>>>(part2, bng + 32, bnb + 32, Wd + 1024, bd + 32, Wdp, bdp);
    lspd_final<<<512, 512, 0, stream>>>(L1, R1, Wdp, bdp, dg + 32, db + 32, Wf, bf, out);
}

// Round 10
// 637.532 us; speedup vs baseline: 2.6785x; 1.0297x over previous
//
#include <hip/hip_runtime.h>

// LSPD_43404939493531: bidirectional 2-layer GRU (B=512,T=512,U=32) + BN folds + dense head.
// R15: exp2-prescale of the z/r gate logits. gru1 is VALU-issue-bound (active-SIMD VALUBusy ~75%,
//     MfmaUtil ~18%); 16 sigmoids/step each spend a v_mul converting to log2 domain before
//     v_exp_f32 (which IS exp2). The -log2(e) factor is linear -> folded into every z/r-feeding
//     weight/bias/table column: tab z/r cols (lspd_tab), gru0's u0/u1/bZ/bR (at load), fold1's
//     Wp z/r cols + b4 z/r slots, gru1's AUz/AUr (at load). Gates become rcp(1+exp2(y)).
//     Removes 16 VALU inst/step from gru1, 2/step from gru0. No structural/memory changes
//     (R12's SMT and R9's MFMA-gru0 both regressed; this is the safe certain lever).
//     gru0 = R7 VALU form; gru1 = R11 MFMA form; feeders as R14.

#define Bsz 512
#define Tsz 512

#define NL2E (-1.4426950408889634f)

typedef unsigned uintv2 __attribute__((ext_vector_type(2)));
typedef _Float16 half8 __attribute__((ext_vector_type(8)));
typedef float f32x4 __attribute__((ext_vector_type(4)));

union H8 { unsigned u[4]; half8 h; };

__device__ __forceinline__ float exp2_f(float x) {
#if __has_builtin(__builtin_amdgcn_exp2f)
    return __builtin_amdgcn_exp2f(x);
#else
    return exp2f(x);
#endif
}
// sigmoid of the ORIGINAL logit, given y = -log2e * logit (prescaled upstream)
__device__ __forceinline__ float nsig(float y) {
    return __builtin_amdgcn_rcpf(1.0f + exp2_f(y));
}

// ---- cross-lane swaps (VALU pipe), two-result form ----
__device__ __forceinline__ uintv2 p16(unsigned a, unsigned b) {
#if __has_builtin(__builtin_amdgcn_permlane16_swap)
    return __builtin_amdgcn_permlane16_swap(a, b, false, false);
#else
    asm("v_permlane16_swap_b32 %0, %1" : "+v"(a), "+v"(b));
    uintv2 r; r.x = a; r.y = b; return r;
#endif
}
__device__ __forceinline__ uintv2 p32(unsigned a, unsigned b) {
#if __has_builtin(__builtin_amdgcn_permlane32_swap)
    return __builtin_amdgcn_permlane32_swap(a, b, false, false);
#else
    asm("v_permlane32_swap_b32 %0, %1" : "+v"(a), "+v"(b));
    uintv2 r; r.x = a; r.y = b; return r;
#endif
}

// ---- R7 VALU-GRU primitives (gru0) ----
__device__ __forceinline__ void plswap16_f(float& a, float& b) {
    uintv2 r = p16(__float_as_uint(a), __float_as_uint(b));
    a = __uint_as_float(r.x);
    b = __uint_as_float(r.y);
}
__device__ __forceinline__ void plswap16_i(int& a, int& b) {
    uintv2 r = p16((unsigned)a, (unsigned)b);
    a = (int)r.x;
    b = (int)r.y;
}
__device__ __forceinline__ float xhalfsum(float a) {   // a[lane] + a[lane^32]
    uintv2 r = p32(__float_as_uint(a), __float_as_uint(a));
    return __uint_as_float(r.x) + __uint_as_float(r.y);
}

// DPP row_newbcast:n (ctrl 0x150+n): broadcast in-row lane n to the whole 16-lane row
#define NB_F(d, s, n) d = __int_as_float(__builtin_amdgcn_update_dpp(0, __float_as_int(s), 0x150 + n, 0xF, 0xF, true))
#define NB_I(d, s, n) d = __builtin_amdgcn_update_dpp(0, (s), 0x150 + n, 0xF, 0xF, true)
#define BCAST16F(A, S)                                                         \
    NB_F(A[0], S, 0);  NB_F(A[1], S, 1);  NB_F(A[2], S, 2);  NB_F(A[3], S, 3); \
    NB_F(A[4], S, 4);  NB_F(A[5], S, 5);  NB_F(A[6], S, 6);  NB_F(A[7], S, 7); \
    NB_F(A[8], S, 8);  NB_F(A[9], S, 9);  NB_F(A[10], S, 10); NB_F(A[11], S, 11); \
    NB_F(A[12], S, 12); NB_F(A[13], S, 13); NB_F(A[14], S, 14); NB_F(A[15], S, 15)
#define BCAST16I(A, S)                                                         \
    NB_I(A[0], S, 0);  NB_I(A[1], S, 1);  NB_I(A[2], S, 2);  NB_I(A[3], S, 3); \
    NB_I(A[4], S, 4);  NB_I(A[5], S, 5);  NB_I(A[6], S, 6);  NB_I(A[7], S, 7); \
    NB_I(A[8], S, 8);  NB_I(A[9], S, 9);  NB_I(A[10], S, 10); NB_I(A[11], S, 11); \
    NB_I(A[12], S, 12); NB_I(A[13], S, 13); NB_I(A[14], S, 14); NB_I(A[15], S, 15)

// ---- R11 MFMA-GRU primitives (gru1) ----
// Fixed routing network: 4 packed words (2 ch each, C-layout) -> 4 B-fragment words.
__device__ __forceinline__ void route4(unsigned P0, unsigned P1, unsigned P2, unsigned P3,
                                       unsigned& W0, unsigned& W1, unsigned& W2, unsigned& W3)
{
    uintv2 m = p32(P0, P2);
    uintv2 a = p16(m.x, m.y);
    uintv2 n = p32(P1, P3);
    uintv2 c = p16(n.x, n.y);
    W0 = a.x; W2 = a.y; W1 = c.x; W3 = c.y;
}

__device__ __forceinline__ unsigned pk16(float a, float b) {
    auto h = __builtin_amdgcn_cvt_pkrtz(a, b);   // __fp16 ext_vector_type(2)
    return __builtin_bit_cast(unsigned, h);
}

__device__ __forceinline__ H8 make_B(float v0, float v1, float v2, float v3,
                                     float v4, float v5, float v6, float v7)
{
    unsigned P0 = pk16(v0, v1), P1 = pk16(v2, v3);
    unsigned P2 = pk16(v4, v5), P3 = pk16(v6, v7);
    H8 b;
    route4(P0, P1, P2, P3, b.u[0], b.u[1], b.u[2], b.u[3]);
    return b;
}

// calibrate: cs[e] = channel whose value lands in B-slot e for this lane
__device__ __forceinline__ void calib_slots(int lane, int cs[8]) {
    unsigned q = (unsigned)(lane >> 4) & 3u;
    unsigned c0 = 4u * q, c1 = 16u + 4u * q;
    unsigned P0 = c0 | ((c0 + 1u) << 16);
    unsigned P1 = (c0 + 2u) | ((c0 + 3u) << 16);
    unsigned P2 = c1 | ((c1 + 1u) << 16);
    unsigned P3 = (c1 + 2u) | ((c1 + 3u) << 16);
    unsigned W0, W1, W2, W3;
    route4(P0, P1, P2, P3, W0, W1, W2, W3);
    cs[0] = W0 & 0xffff; cs[1] = W0 >> 16;
    cs[2] = W1 & 0xffff; cs[3] = W1 >> 16;
    cs[4] = W2 & 0xffff; cs[5] = W2 >> 16;
    cs[6] = W3 & 0xffff; cs[7] = W3 >> 16;
}

// A-tile: row = lane&15 (gate row within tile), slot e multiplies B slot e -> load via cs[]
__device__ __forceinline__ H8 load_A(const float* __restrict__ M, const int cs[8], int gcol, float scale) {
    H8 a;
#pragma unroll
    for (int e = 0; e < 4; ++e)
        a.u[e] = pk16(scale * M[cs[2 * e] * 96 + gcol], scale * M[cs[2 * e + 1] * 96 + gcol]);
    return a;
}

__device__ __forceinline__ f32x4 mfma16(const H8& a, const H8& b, f32x4 c) {
    return __builtin_amdgcn_mfma_f32_16x16x32_f16(a.h, b.h, c, 0, 0, 0);
}

// az, ar already in -log2e domain; ah/ai linear
__device__ __forceinline__ float gate1(float az, float ar, float ah, float ai, float h) {
    float z = nsig(az);
    float r = nsig(ar);
    float hh = fmaxf(0.f, fmaf(r, ah, ai));
    return hh + z * (h - hh);
}

// ---------------- K1: argmax over D=128, grid-stride, one wave per row, 32 rows/wave ----------------
__global__ __launch_bounds__(256) void lspd_argmax(const float* __restrict__ x, int* __restrict__ idxT)
{
    int wv = threadIdx.x >> 6, lane = threadIdx.x & 63;
    int wave_id = blockIdx.x * 4 + wv;            // 0..8191
    for (int r = 0; r < 32; ++r) {
        long p = (long)wave_id + (long)r * 8192;  // p = b*512 + t, all 262144 rows covered
        const float* xp = x + p * 128;
        float2 a = *(const float2*)(xp + 2 * lane);
        float v0 = a.x; int i0 = 2 * lane;
        if (a.y > v0) { v0 = a.y; i0 = 2 * lane + 1; }   // ties keep lower index
#pragma unroll
        for (int d = 1; d < 64; d <<= 1) {
            float ov = __shfl_xor(v0, d, 64);
            int   oi = __shfl_xor(i0, d, 64);
            if (ov > v0 || (ov == v0 && oi < i0)) { v0 = ov; i0 = oi; }
        }
        if (lane == 0) idxT[p] = i0;
    }
}

// ---------------- K0: layer-0 input tables; z/r columns pre-scaled by -log2e ----------------
__global__ __launch_bounds__(256) void lspd_tab(
    const float* __restrict__ emb, const float* __restrict__ Wl, const float* __restrict__ bl,
    const float* __restrict__ Wr, const float* __restrict__ br,
    float* __restrict__ tabL, float* __restrict__ tabR)
{
    int flat = blockIdx.x * 256 + threadIdx.x;    // 0..24575
    int dir = flat / 12288;
    int r = flat % 12288;
    int i = r / 96, g = r % 96;
    const float* W  = dir ? Wr : Wl;              // layer 0 at base
    const float* bb = dir ? br : bl;              // b[0][0] input bias at base
    float acc = bb[g];
#pragma unroll
    for (int k = 0; k < 32; ++k) acc = fmaf(emb[i * 32 + k], W[k * 96 + g], acc);
    if (g < 64) acc *= NL2E;                      // z,r logits -> -log2e domain
    (dir ? tabR : tabL)[r] = acc;
}

// ---------------- K2: layer-0 GRU (R7 VALU form), 1 chain per wave, 1024 waves ----------------
__global__ __launch_bounds__(64)
__attribute__((amdgpu_waves_per_eu(1, 1)))
void lspd_gru0(
    const int* __restrict__ idxT, const float* __restrict__ tabL, const float* __restrict__ tabR,
    const float* __restrict__ Ul, const float* __restrict__ Ur,
    const float* __restrict__ bl, const float* __restrict__ br,
    float* __restrict__ Lout, float* __restrict__ Rout)
{
    int wid = blockIdx.x;
    int dir = wid >> 9;
    int b = wid & 511;
    int lane = threadIdx.x;
    int half = lane >> 5, c = lane & 31;
    const float* U    = dir ? Ur : Ul;
    const float* tab  = dir ? tabR : tabL;
    const float* brec = (dir ? br : bl) + 96;     // layer-0 recurrent bias b[0][1]
    float* out        = dir ? Rout : Lout;

    // ---- permutation self-calibration: kk[j] = channel whose h lands in hk[j] ----
    int ksA = c, ksB = c;
    plswap16_i(ksA, ksB);
    bool selA = ((ksA >> 4) == half);
    int ksel = selA ? ksA : ksB;
    int kk[16];
    BCAST16I(kk, ksel);

    float u0[16], u1[16], u2[16];
#pragma unroll
    for (int j = 0; j < 16; ++j) {
        u0[j] = NL2E * U[kk[j] * 96 + c];          // z (scaled)
        u1[j] = NL2E * U[kk[j] * 96 + 32 + c];     // r (scaled)
        u2[j] = U[kk[j] * 96 + 64 + c];            // h (linear)
    }
    float bZ = half ? 0.f : NL2E * brec[c];
    float bR = half ? 0.f : NL2E * brec[32 + c];
    float bH = half ? 0.f : brec[64 + c];
#pragma unroll
    for (int j = 0; j < 16; ++j) {
        asm volatile("" : "+v"(u0[j]), "+v"(u1[j]), "+v"(u2[j]));
    }
    asm volatile("" : "+v"(bZ), "+v"(bR), "+v"(bH));

    const int* idxrow = idxT + (long)b * Tsz;
    if (lane < 32) out[(((long)(dir ? Tsz - 1 : 0)) * Bsz + b) * 32 + c] = 0.f;  // boundary zero

#define TT0(s) (dir ? (Tsz - 2 - (s)) : (1 + (s)))
    long ob = ((long)TT0(0) * Bsz + b) * 32 + c;
    long ostride = (long)(dir ? -1 : 1) * Bsz * 32;

    // 4-slot gi pipeline (gather 4 steps ahead), idx 8 ahead
    float g0z, g0r, g0h, g1z, g1r, g1h, g2z, g2r, g2h, g3z, g3r, g3h;
    { int i = idxrow[TT0(0)]; g0z = tab[i * 96 + c]; g0r = tab[i * 96 + 32 + c]; g0h = tab[i * 96 + 64 + c]; }
    { int i = idxrow[TT0(1)]; g1z = tab[i * 96 + c]; g1r = tab[i * 96 + 32 + c]; g1h = tab[i * 96 + 64 + c]; }
    { int i = idxrow[TT0(2)]; g2z = tab[i * 96 + c]; g2r = tab[i * 96 + 32 + c]; g2h = tab[i * 96 + 64 + c]; }
    { int i = idxrow[TT0(3)]; g3z = tab[i * 96 + c]; g3r = tab[i * 96 + 32 + c]; g3h = tab[i * 96 + 64 + c]; }
    int i0 = idxrow[TT0(4)];
    int i1 = idxrow[TT0(5)];
    int i2 = idxrow[TT0(6)];
    int i3 = idxrow[TT0(7)];
    float h = 0.f;

#define GSTEP(GZ, GR, GH, IREG, SNEXT)                                         \
    {                                                                          \
        float ha = h, hb = h;                                                  \
        plswap16_f(ha, hb);                                                    \
        float hs = selA ? ha : hb;                                             \
        float hk[16];                                                          \
        BCAST16F(hk, hs);                                                      \
        float az = bZ, ar = bR, ah = bH;                                       \
        _Pragma("unroll")                                                      \
        for (int n = 0; n < 16; ++n) {                                         \
            az = fmaf(hk[n], u0[n], az);                                       \
            ar = fmaf(hk[n], u1[n], ar);                                       \
            ah = fmaf(hk[n], u2[n], ah);                                       \
        }                                                                      \
        az = xhalfsum(az); ar = xhalfsum(ar); ah = xhalfsum(ah);               \
        float z = nsig(az + GZ);                                               \
        float r = nsig(ar + GR);                                               \
        float hh = fmaxf(0.f, fmaf(r, ah, GH));                                \
        h = hh + z * (h - hh);                                                 \
        if (lane < 32) out[ob] = h;                                            \
        ob += ostride;                                                         \
        GZ = tab[IREG * 96 + c];                                               \
        GR = tab[IREG * 96 + 32 + c];                                          \
        GH = tab[IREG * 96 + 64 + c];                                          \
        int sn = (SNEXT); if (sn > Tsz - 2) sn = Tsz - 2;                      \
        IREG = idxrow[TT0(sn)];                                                \
    }

    for (int sb = 0; sb < 508; sb += 4) {
        GSTEP(g0z, g0r, g0h, i0, sb + 8);
        GSTEP(g1z, g1r, g1h, i1, sb + 9);
        GSTEP(g2z, g2r, g2h, i2, sb + 10);
        GSTEP(g3z, g3r, g3h, i3, sb + 11);
    }
    // tail: steps 508, 509, 510 (refills are clamped duplicates, dead)
    GSTEP(g0z, g0r, g0h, i0, 510);
    GSTEP(g1z, g1r, g1h, i1, 510);
    GSTEP(g2z, g2r, g2h, i2, 510);
#undef GSTEP
#undef TT0
}

// ---------------- K3/K5: per-channel sum & sumsq of (L+R), 1024 threads for TLP ----------------
__global__ __launch_bounds__(1024) void lspd_stats(
    const float* __restrict__ A, const float* __restrict__ Bv, float* __restrict__ part)
{
    __shared__ float sS[1024], sQ[1024];
    int tid = threadIdx.x;
    size_t base = (size_t)blockIdx.x * 65536 + tid;
    float s = 0.f, q = 0.f;
    for (int i = 0; i < 64; ++i) {
        size_t ix = base + (size_t)i * 1024;
        float v = A[ix] + Bv[ix];
        s += v; q = fmaf(v, v, q);
    }
    sS[tid] = s; sQ[tid] = q;
    __syncthreads();
    if (tid < 32) {
        float S = 0.f, Q = 0.f;
        for (int j = 0; j < 32; ++j) { S += sS[tid + 32 * j]; Q += sQ[tid + 32 * j]; }
        part[blockIdx.x * 64 + tid] = S;
        part[blockIdx.x * 64 + 32 + tid] = Q;
    }
}

// ---------------- K3b: fold layer-0 BN into layer-1 input weights (z/r cols prescaled) ----------------
__global__ __launch_bounds__(256) void lspd_fold1(
    const float* __restrict__ part, const float* __restrict__ g0, const float* __restrict__ be0,
    const float* __restrict__ Wl, const float* __restrict__ Wr,
    const float* __restrict__ bl, const float* __restrict__ br,
    float* __restrict__ WpL, float* __restrict__ WpR,
    float* __restrict__ b4L, float* __restrict__ b4R)
{
    __shared__ float sc[32], tc[32];
    int tid = threadIdx.x;
    if (tid < 32) {
        float S = 0.f, Q = 0.f;
        for (int p = 0; p < 128; ++p) { S += part[p * 64 + tid]; Q += part[p * 64 + 32 + tid]; }
        const float invN = 1.0f / 262144.0f;
        float m = S * invN;
        float v = Q * invN - m * m;
        float s = g0[tid] * __builtin_amdgcn_rsqf(v + 1e-3f);
        sc[tid] = s; tc[tid] = be0[tid] - s * m;
    }
    __syncthreads();
    for (int idx = tid; idx < 6144; idx += 256) {
        int dir = idx / 3072, e = idx % 3072, k = e / 96, g = e % 96;
        const float* W1 = (dir ? Wr : Wl) + 3072;      // layer 1
        float w = sc[k] * W1[k * 96 + g];
        if (g < 64) w *= NL2E;                          // z,r x-projection -> -log2e domain
        (dir ? WpR : WpL)[e] = w;
    }
    {
        int idx = tid;                                  // 256 entries exactly
        int dir = idx >> 7, slot = idx & 127, sub = slot >> 5, cc = slot & 31;
        const float* bb = (dir ? br : bl) + 192;        // layer-1: [0..95]=input, [96..191]=recurrent
        const float* W1 = (dir ? Wr : Wl) + 3072;
        float r;
        if (sub == 2) {
            r = bb[96 + 64 + cc];                       // rh: recurrent h-bias only
        } else {
            int g = (sub == 3) ? (64 + cc) : (sub * 32 + cc);
            float acc = bb[g];                          // input bias
            for (int k = 0; k < 32; ++k) acc = fmaf(tc[k], W1[k * 96 + g], acc);
            if (sub < 2) acc += bb[96 + g];             // z,r: + recurrent bias
            r = acc;
        }
        if (sub < 2) r *= NL2E;                         // z,r total bias -> -log2e domain
        (dir ? b4R : b4L)[slot] = r;
    }
}

// ---------------- K4: layer-1 GRU (R11 MFMA form), 16 batch rows per wave, 64 waves ----------------
__global__ __launch_bounds__(64)
__attribute__((amdgpu_waves_per_eu(1, 1)))
void lspd_gru1(
    const float* __restrict__ L0, const float* __restrict__ R0,
    const float* __restrict__ WpL, const float* __restrict__ WpR,
    const float* __restrict__ b4L, const float* __restrict__ b4R,
    const float* __restrict__ Ul1, const float* __restrict__ Ur1,
    float* __restrict__ Lout, float* __restrict__ Rout)
{
    int bid = blockIdx.x;
    int dir = bid >> 5;
    int bg  = bid & 31;
    int lane = threadIdx.x;
    int rl = lane & 15;
    int q  = lane >> 4;
    int b  = bg * 16 + rl;
    const float* U  = dir ? Ur1 : Ul1;
    const float* Wp = dir ? WpR : WpL;
    const float* b4 = dir ? b4R : b4L;
    float* out      = dir ? Rout : Lout;

    int cs[8];
    calib_slots(lane, cs);

    // Wp already prescaled by fold1 (z/r cols); U z/r scaled here at load
    H8 AWz0 = load_A(Wp, cs, 0  + rl, 1.0f), AWz1 = load_A(Wp, cs, 16 + rl, 1.0f);
    H8 AWr0 = load_A(Wp, cs, 32 + rl, 1.0f), AWr1 = load_A(Wp, cs, 48 + rl, 1.0f);
    H8 AWh0 = load_A(Wp, cs, 64 + rl, 1.0f), AWh1 = load_A(Wp, cs, 80 + rl, 1.0f);
    H8 AUz0 = load_A(U, cs, 0  + rl, NL2E),  AUz1 = load_A(U, cs, 16 + rl, NL2E);
    H8 AUr0 = load_A(U, cs, 32 + rl, NL2E),  AUr1 = load_A(U, cs, 48 + rl, NL2E);
    H8 AUh0 = load_A(U, cs, 64 + rl, 1.0f),  AUh1 = load_A(U, cs, 80 + rl, 1.0f);
    // bias fragments: b4 = [z total(32,scaled) | r total(32,scaled) | rh rec-bias(32) | ih folded(32)]
    f32x4 BZ0 = *(const f32x4*)(b4 + 0   + 4 * q);
    f32x4 BZ1 = *(const f32x4*)(b4 + 16  + 4 * q);
    f32x4 BR0 = *(const f32x4*)(b4 + 32  + 4 * q);
    f32x4 BR1 = *(const f32x4*)(b4 + 48  + 4 * q);
    f32x4 BH0 = *(const f32x4*)(b4 + 64  + 4 * q);
    f32x4 BH1 = *(const f32x4*)(b4 + 80  + 4 * q);
    f32x4 BI0 = *(const f32x4*)(b4 + 96  + 4 * q);
    f32x4 BI1 = *(const f32x4*)(b4 + 112 + 4 * q);

#define XBASE(s) (((long)(dir ? (Tsz - 2 - (s)) : (1 + (s))) * Bsz + b) * 32)
    {
        long zb = ((long)(dir ? Tsz - 1 : 0) * Bsz + b) * 32;
        float4 z4 = make_float4(0.f, 0.f, 0.f, 0.f);
        *(float4*)(out + zb + 4 * q) = z4;
        *(float4*)(out + zb + 16 + 4 * q) = z4;
    }
    long ob = XBASE(0);
    long ostride = (long)(dir ? -1 : 1) * Bsz * 32;

    // P double-buffer: x-projection results (z,r chained-base; i = ih incl folded bias)
    f32x4 PAz0, PAz1, PAr0, PAr1, PAi0, PAi1;
    f32x4 PBz0, PBz1, PBr0, PBr1, PBi0, PBi1;
    // prologue: P_A for step 0 from x(0)
    {
        long n0 = XBASE(0);
        float4 ta = *(const float4*)(L0 + n0 + 4 * q);
        float4 tb = *(const float4*)(L0 + n0 + 16 + 4 * q);
        float4 tc = *(const float4*)(R0 + n0 + 4 * q);
        float4 td = *(const float4*)(R0 + n0 + 16 + 4 * q);
        H8 Bx = make_B(ta.x + tc.x, ta.y + tc.y, ta.z + tc.z, ta.w + tc.w,
                       tb.x + td.x, tb.y + td.y, tb.z + td.z, tb.w + td.w);
        PAz0 = mfma16(AWz0, Bx, BZ0);
        PAz1 = mfma16(AWz1, Bx, BZ1);
        PAr0 = mfma16(AWr0, Bx, BR0);
        PAr1 = mfma16(AWr1, Bx, BR1);
        PAi0 = mfma16(AWh0, Bx, BI0);
        PAi1 = mfma16(AWh1, Bx, BI1);
    }
    // x slots j=0..3 hold x(1+j); slot used at step s (s%4==j) for Bx(s+1), refilled <- x(s+5)
    float4 la0, lb0, ra0, rb0, la1, lb1, ra1, rb1;
    float4 la2, lb2, ra2, rb2, la3, lb3, ra3, rb3;
    {
        long n1 = XBASE(1);
        la0 = *(const float4*)(L0 + n1 + 4 * q); lb0 = *(const float4*)(L0 + n1 + 16 + 4 * q);
        ra0 = *(const float4*)(R0 + n1 + 4 * q); rb0 = *(const float4*)(R0 + n1 + 16 + 4 * q);
        long n2 = XBASE(2);
        la1 = *(const float4*)(L0 + n2 + 4 * q); lb1 = *(const float4*)(L0 + n2 + 16 + 4 * q);
        ra1 = *(const float4*)(R0 + n2 + 4 * q); rb1 = *(const float4*)(R0 + n2 + 16 + 4 * q);
        long n3 = XBASE(3);
        la2 = *(const float4*)(L0 + n3 + 4 * q); lb2 = *(const float4*)(L0 + n3 + 16 + 4 * q);
        ra2 = *(const float4*)(R0 + n3 + 4 * q); rb2 = *(const float4*)(R0 + n3 + 16 + 4 * q);
        long n4 = XBASE(4);
        la3 = *(const float4*)(L0 + n4 + 4 * q); lb3 = *(const float4*)(L0 + n4 + 16 + 4 * q);
        ra3 = *(const float4*)(R0 + n4 + 4 * q); rb3 = *(const float4*)(R0 + n4 + 16 + 4 * q);
    }
    float h0 = 0.f, h1 = 0.f, h2 = 0.f, h3 = 0.f, h4 = 0.f, h5 = 0.f, h6 = 0.f, h7 = 0.f;

    // step s: consume P (made from x(s)); produce Q (for s+1) from slot = x(s+1); refill slot.
    // Critical path: make_B(h) -> 1 chained MFMA -> gates. Q-production fills hazard window.
#define STEP1(XLA, XLB, XRA, XRB, Pz0, Pz1, Pr0, Pr1, Pi0, Pi1,                \
              Qz0, Qz1, Qr0, Qr1, Qi0, Qi1, SNEXT)                             \
    {                                                                          \
        H8 Bh = make_B(h0, h1, h2, h3, h4, h5, h6, h7);                        \
        f32x4 Cz0 = mfma16(AUz0, Bh, Pz0);                                     \
        f32x4 Cz1 = mfma16(AUz1, Bh, Pz1);                                     \
        f32x4 Cr0 = mfma16(AUr0, Bh, Pr0);                                     \
        f32x4 Cr1 = mfma16(AUr1, Bh, Pr1);                                     \
        f32x4 Ch0 = mfma16(AUh0, Bh, BH0);                                     \
        f32x4 Ch1 = mfma16(AUh1, Bh, BH1);                                     \
        H8 Bx = make_B(XLA.x + XRA.x, XLA.y + XRA.y, XLA.z + XRA.z,            \
                       XLA.w + XRA.w, XLB.x + XRB.x, XLB.y + XRB.y,            \
                       XLB.z + XRB.z, XLB.w + XRB.w);                          \
        Qz0 = mfma16(AWz0, Bx, BZ0);                                           \
        Qz1 = mfma16(AWz1, Bx, BZ1);                                           \
        Qr0 = mfma16(AWr0, Bx, BR0);                                           \
        Qr1 = mfma16(AWr1, Bx, BR1);                                           \
        Qi0 = mfma16(AWh0, Bx, BI0);                                           \
        Qi1 = mfma16(AWh1, Bx, BI1);                                           \
        int sn = (SNEXT); if (sn > Tsz - 2) sn = Tsz - 2;                      \
        long nb = XBASE(sn);                                                   \
        XLA = *(const float4*)(L0 + nb + 4 * q);                               \
        XLB = *(const float4*)(L0 + nb + 16 + 4 * q);                          \
        XRA = *(const float4*)(R0 + nb + 4 * q);                               \
        XRB = *(const float4*)(R0 + nb + 16 + 4 * q);                          \
        h0 = gate1(Cz0.x, Cr0.x, Ch0.x, Pi0.x, h0);                            \
        h1 = gate1(Cz0.y, Cr0.y, Ch0.y, Pi0.y, h1);                            \
        h2 = gate1(Cz0.z, Cr0.z, Ch0.z, Pi0.z, h2);                            \
        h3 = gate1(Cz0.w, Cr0.w, Ch0.w, Pi0.w, h3);                            \
        h4 = gate1(Cz1.x, Cr1.x, Ch1.x, Pi1.x, h4);                            \
        h5 = gate1(Cz1.y, Cr1.y, Ch1.y, Pi1.y, h5);                            \
        h6 = gate1(Cz1.z, Cr1.z, Ch1.z, Pi1.z, h6);                            \
        h7 = gate1(Cz1.w, Cr1.w, Ch1.w, Pi1.w, h7);                            \
        *(float4*)(out + ob + 4 * q) = make_float4(h0, h1, h2, h3);            \
        *(float4*)(out + ob + 16 + 4 * q) = make_float4(h4, h5, h6, h7);       \
        ob += ostride;                                                         \
    }

    for (int sb = 0; sb < 508; sb += 4) {
        STEP1(la0, lb0, ra0, rb0,
              PAz0, PAz1, PAr0, PAr1, PAi0, PAi1,
              PBz0, PBz1, PBr0, PBr1, PBi0, PBi1, sb + 5);
        STEP1(la1, lb1, ra1, rb1,
              PBz0, PBz1, PBr0, PBr1, PBi0, PBi1,
              PAz0, PAz1, PAr0, PAr1, PAi0, PAi1, sb + 6);
        STEP1(la2, lb2, ra2, rb2,
              PAz0, PAz1, PAr0, PAr1, PAi0, PAi1,
              PBz0, PBz1, PBr0, PBr1, PBi0, PBi1, sb + 7);
        STEP1(la3, lb3, ra3, rb3,
              PBz0, PBz1, PBr0, PBr1, PBi0, PBi1,
              PAz0, PAz1, PAr0, PAr1, PAi0, PAi1, sb + 8);
    }
    // tail: steps 508, 509, 510 (Q production + refills are dead/clamped)
    STEP1(la0, lb0, ra0, rb0,
          PAz0, PAz1, PAr0, PAr1, PAi0, PAi1,
          PBz0, PBz1, PBr0, PBr1, PBi0, PBi1, 510);
    STEP1(la1, lb1, ra1, rb1,
          PBz0, PBz1, PBr0, PBr1, PBi0, PBi1,
          PAz0, PAz1, PAr0, PAr1, PAi0, PAi1, 510);
    STEP1(la2, lb2, ra2, rb2,
          PAz0, PAz1, PAr0, PAr1, PAi0, PAi1,
          PBz0, PBz1, PBr0, PBr1, PBi0, PBi1, 510);
#undef STEP1
#undef XBASE
}

// ---------------- K5b: fold layer-1 BN into dense-1 weights ----------------
__global__ __launch_bounds__(256) void lspd_fold2(
    const float* __restrict__ part, const float* __restrict__ g1, const float* __restrict__ be1,
    const float* __restrict__ Wd1, const float* __restrict__ bd1,
    float* __restrict__ Wdp, float* __restrict__ bdp)
{
    __shared__ float sc[32], tc[32];
    int tid = threadIdx.x;
    if (tid < 32) {
        float S = 0.f, Q = 0.f;
        for (int p = 0; p < 128; ++p) { S += part[p * 64 + tid]; Q += part[p * 64 + 32 + tid]; }
        const float invN = 1.0f / 262144.0f;
        float m = S * invN;
        float v = Q * invN - m * m;
        float s = g1[tid] * __builtin_amdgcn_rsqf(v + 1e-3f);
        sc[tid] = s; tc[tid] = be1[tid] - s * m;
    }
    __syncthreads();
    for (int idx = tid; idx < 1024; idx += 256) {
        int k = idx >> 5;
        Wdp[idx] = sc[k] * Wd1[idx];
    }
    if (tid < 32) {
        float acc = bd1[tid];
        for (int k = 0; k < 32; ++k) acc = fmaf(tc[k], Wd1[k * 32 + tid], acc);
        bdp[tid] = acc;
    }
}

// ---------------- K6: dense + per-t batch BN + classifier + softmax; one block per t ----------------
__global__ __launch_bounds__(512) void lspd_final(
    const float* __restrict__ L1a, const float* __restrict__ R1a,
    const float* __restrict__ Wdp, const float* __restrict__ bdp,
    const float* __restrict__ dg, const float* __restrict__ db,
    const float* __restrict__ Wf, const float* __restrict__ bfv,
    float* __restrict__ outp)
{
    __shared__ alignas(16) float sW[1024];
    __shared__ float sb[32], sWf[352], sbf[16], sS[32], sT[32];
    __shared__ float redS[8][32], redQ[8][32];
    int tid = threadIdx.x, t = blockIdx.x;
    for (int i = tid; i < 1024; i += 512) sW[i] = Wdp[i];
    if (tid < 32)  sb[tid] = bdp[tid];
    if (tid < 352) sWf[tid] = Wf[tid];
    if (tid < 11)  sbf[tid] = bfv[tid];
    __syncthreads();

    size_t base = ((size_t)t * Bsz + tid) * 32;
    float xv[32];
#pragma unroll
    for (int c2 = 0; c2 < 32; c2 += 4) {
        float4 a = *(const float4*)(L1a + base + c2);
        float4 b = *(const float4*)(R1a + base + c2);
        xv[c2 + 0] = a.x + b.x; xv[c2 + 1] = a.y + b.y;
        xv[c2 + 2] = a.z + b.z; xv[c2 + 3] = a.w + b.w;
    }
    float o[32];
#pragma unroll
    for (int g = 0; g < 32; ++g) o[g] = sb[g];
#pragma unroll
    for (int k = 0; k < 32; ++k) {
        float xk = xv[k];
#pragma unroll
        for (int g4 = 0; g4 < 8; ++g4) {
            float4 w = *(const float4*)(sW + k * 32 + g4 * 4);   // same-address LDS broadcast
            o[g4 * 4 + 0] = fmaf(xk, w.x, o[g4 * 4 + 0]);
            o[g4 * 4 + 1] = fmaf(xk, w.y, o[g4 * 4 + 1]);
            o[g4 * 4 + 2] = fmaf(xk, w.z, o[g4 * 4 + 2]);
            o[g4 * 4 + 3] = fmaf(xk, w.w, o[g4 * 4 + 3]);
        }
    }
#pragma unroll
    for (int g = 0; g < 32; ++g) o[g] = fmaxf(o[g], 0.f);

    // per-(t,channel) stats over batch (within block)
    int wv = tid >> 6, lane = tid & 63;
    for (int g = 0; g < 32; ++g) {
        float s = o[g], q = o[g] * o[g];
        for (int d = 1; d < 64; d <<= 1) {
            s += __shfl_xor(s, d, 64);
            q += __shfl_xor(q, d, 64);
        }
        if (lane == 0) { redS[wv][g] = s; redQ[wv][g] = q; }
    }
    __syncthreads();
    if (tid < 32) {
        float S = 0.f, Q = 0.f;
        for (int w2 = 0; w2 < 8; ++w2) { S += redS[w2][tid]; Q += redQ[w2][tid]; }
        float m = S * (1.0f / 512.0f);
        float v = Q * (1.0f / 512.0f) - m * m;
        float s = dg[tid] * __builtin_amdgcn_rsqf(v + 1e-3f);
        sS[tid] = s; sT[tid] = db[tid] - s * m;
    }
    __syncthreads();

    float lg[11];
#pragma unroll
    for (int n = 0; n < 11; ++n) lg[n] = sbf[n];
#pragma unroll
    for (int g = 0; g < 32; ++g) {
        float no = fmaf(o[g], sS[g], sT[g]);
#pragma unroll
        for (int n = 0; n < 11; ++n) lg[n] = fmaf(no, sWf[g * 11 + n], lg[n]);
    }
    float mx = lg[0];
#pragma unroll
    for (int n = 1; n < 11; ++n) mx = fmaxf(mx, lg[n]);
    float sum = 0.f;
#pragma unroll
    for (int n = 0; n < 11; ++n) { lg[n] = __expf(lg[n] - mx); sum += lg[n]; }
    float inv = __builtin_amdgcn_rcpf(sum);
    float* op = outp + ((size_t)tid * Tsz + t) * 11;
#pragma unroll
    for (int n = 0; n < 11; ++n) op[n] = lg[n] * inv;
}

extern "C" void kernel_launch(void* const* d_in, const int* in_sizes, int n_in,
                              void* d_out, int out_size, void* d_ws, size_t ws_size,
                              hipStream_t stream)
{
    (void)in_sizes; (void)n_in; (void)out_size; (void)ws_size;
    const float* x   = (const float*)d_in[0];
    const float* emb = (const float*)d_in[1];
    const float* Wl  = (const float*)d_in[2];
    const float* Ul  = (const float*)d_in[3];
    const float* bl  = (const float*)d_in[4];
    const float* Wr  = (const float*)d_in[5];
    const float* Ur  = (const float*)d_in[6];
    const float* br  = (const float*)d_in[7];
    const float* bng = (const float*)d_in[8];
    const float* bnb = (const float*)d_in[9];
    const float* Wd  = (const float*)d_in[10];
    const float* bd  = (const float*)d_in[11];
    const float* dg  = (const float*)d_in[12];
    const float* db  = (const float*)d_in[13];
    const float* Wf  = (const float*)d_in[14];
    const float* bf  = (const float*)d_in[15];
    float* out = (float*)d_out;

    float* ws = (float*)d_ws;
    float* L0 = ws;
    float* R0 = L0 + 8388608;
    float* L1 = R0 + 8388608;
    float* R1 = L1 + 8388608;
    float* rest = R1 + 8388608;
    int* idxT   = (int*)rest;            // 262144 ints
    float* tabL = rest + 262144;
    float* tabR = tabL + 12288;
    float* part1 = tabR + 12288;         // 8192
    float* part2 = part1 + 8192;         // 8192
    float* WpL = part2 + 8192;           // 3072
    float* WpR = WpL + 3072;
    float* b4L = WpR + 3072;             // 128
    float* b4R = b4L + 128;
    float* Wdp = b4R + 128;              // 1024
    float* bdp = Wdp + 1024;             // 32

    lspd_argmax<<<2048, 256, 0, stream>>>(x, idxT);
    lspd_tab<<<96, 256, 0, stream>>>(emb, Wl, bl, Wr, br, tabL, tabR);
    lspd_gru0<<<1024, 64, 0, stream>>>(idxT, tabL, tabR, Ul, Ur, bl, br, L0, R0);
    lspd_stats<<<128, 1024, 0, stream>>>(L0, R0, part1);
    lspd_fold1<<<1, 256, 0, stream>>>(part1, bng, bnb, Wl, Wr, bl, br, WpL, WpR, b4L, b4R);
    lspd_gru1<<<64, 64, 0, stream>>>(L0, R0, WpL, WpR, b4L, b4R, Ul + 3072, Ur + 3072, L1, R1);
    lspd_stats<<<128, 1024, 0, stream>>>(L1, R1, part2);
    lspd_fold2<<<1, 256, 0, stream>>>(part2, bng + 32, bnb + 32, Wd + 1024, bd + 32, Wdp, bdp);
    lspd_final<<<512, 512, 0, stream>>>(L1, R1, Wdp, bdp, dg + 32, db + 32, Wf, bf, out);
}